// Round 7
// baseline (193.521 us; speedup 1.0000x reference)
//
#include <hip/hip_runtime.h>
#include <hip/hip_bf16.h>
#include <cstdint>
#include <cstddef>

#define B_   16
#define N_   1024
#define C_   384
#define H_   6
#define DFF_ 1536
#define R_   16384   // B_*N_

typedef __attribute__((ext_vector_type(8))) __bf16 bf16x8;
typedef __attribute__((ext_vector_type(4))) float  f32x4;
typedef __attribute__((ext_vector_type(8))) unsigned short u16x8;
typedef __attribute__((ext_vector_type(4))) unsigned short u16x4;

__device__ __forceinline__ float bf2f(unsigned short u){
    unsigned int x = ((unsigned int)u) << 16;
    return __builtin_bit_cast(float, x);
}
__device__ __forceinline__ unsigned short f2bf(float f){
    return __builtin_bit_cast(unsigned short, __float2bfloat16(f));
}
__device__ __forceinline__ unsigned int cvt_pk_bf16(float a, float b){
    unsigned int r;
    asm("v_cvt_pk_bf16_f32 %0, %1, %2" : "=v"(r) : "v"(a), "v"(b));
    return r;   // lo = bf16(a), hi = bf16(b)
}
// raw v_exp_f32 (2^x). Args provably in [-45,0] -> no OCML range/denorm fixup needed.
__device__ __forceinline__ float fast_exp2(float x){
    float r;
    asm("v_exp_f32 %0, %1" : "=v"(r) : "v"(x));
    return r;
}
__device__ __forceinline__ void gload16(const void* g, void* l){
    __builtin_amdgcn_global_load_lds(
        (const __attribute__((address_space(1))) unsigned int*)g,
        (__attribute__((address_space(3))) unsigned int*)l, 16, 0, 0);
}
// exact-GELU via Abramowitz-Stegun 7.1.25 erf approx (|err| <= 2.5e-5)
__device__ __forceinline__ float gelu_f(float u){
    float z  = fabsf(u) * 0.70710678118654752f;
    float t  = __builtin_amdgcn_rcpf(1.0f + 0.47047f*z);
    float e  = __expf(-z*z);
    float p  = t*(0.3480242f + t*(-0.0958798f + t*0.7478556f));
    float er = 1.0f - p*e;                       // erf(z), z>=0
    return 0.5f*u*(1.0f + copysignf(er, u));
}
__device__ __forceinline__ float ldv(const float* p, size_t i){ return p[i]; }
__device__ __forceinline__ float ldv(const __hip_bfloat16* p, size_t i){ return __bfloat162float(p[i]); }

// ---------------- LN1 + all-weight fp32->bf16 convert, one launch ----------------
__global__ __launch_bounds__(256) void ln1_cvt_kernel(
    const float* __restrict__ x, const float* __restrict__ g,
    const float* __restrict__ b, __hip_bfloat16* __restrict__ out,
    const float* __restrict__ i0, __hip_bfloat16* __restrict__ o0, int n0,
    const float* __restrict__ i1, __hip_bfloat16* __restrict__ o1, int n1,
    const float* __restrict__ i2, __hip_bfloat16* __restrict__ o2, int n2,
    const float* __restrict__ i3, __hip_bfloat16* __restrict__ o3, int n3)
{
    if (blockIdx.x < 4096){
        const int lane = threadIdx.x & 63;
        const int wave = threadIdx.x >> 6;
        const int row  = blockIdx.x*4 + wave;
        const float* xr = x + (size_t)row*C_;
        float v[6];
        float s = 0.f;
        #pragma unroll
        for (int i=0;i<6;i++){ v[i] = xr[lane + i*64]; s += v[i]; }
        #pragma unroll
        for (int m=1;m<64;m<<=1) s += __shfl_xor(s, m);
        const float mean = s * (1.0f/C_);
        float sq = 0.f;
        #pragma unroll
        for (int i=0;i<6;i++){ float d = v[i]-mean; sq += d*d; }
        #pragma unroll
        for (int m=1;m<64;m<<=1) sq += __shfl_xor(sq, m);
        const float rstd = rsqrtf(sq*(1.0f/C_) + 1e-5f);
        #pragma unroll
        for (int i=0;i<6;i++){
            int c = lane + i*64;
            out[(size_t)row*C_ + c] = __float2bfloat16((v[i]-mean)*rstd*g[c] + b[c]);
        }
    } else {
        const int total = n0+n1+n2+n3;
        for (int i = (blockIdx.x-4096)*blockDim.x + threadIdx.x; i < total; i += 1024*blockDim.x){
            int k = i;
            if (k < n0){ o0[k] = __float2bfloat16(i0[k]); continue; }
            k -= n0;
            if (k < n1){ o1[k] = __float2bfloat16(i1[k]); continue; }
            k -= n1;
            if (k < n2){ o2[k] = __float2bfloat16(i2[k]); continue; }
            k -= n2;
            o3[k] = __float2bfloat16(i3[k]);
        }
    }
}

// ---------------- LayerNorm: (fp32|bf16) in -> bf16 out ----------------
template<typename T>
__global__ __launch_bounds__(256) void ln_kernel(
    const T* __restrict__ x, const float* __restrict__ g,
    const float* __restrict__ b, __hip_bfloat16* __restrict__ out)
{
    const int lane = threadIdx.x & 63;
    const int wave = threadIdx.x >> 6;
    const int row  = blockIdx.x*4 + wave;
    const T* xr = x + (size_t)row*C_;
    float v[6];
    float s = 0.f;
    #pragma unroll
    for (int i=0;i<6;i++){ v[i] = ldv(xr, lane + i*64); s += v[i]; }
    #pragma unroll
    for (int m=1;m<64;m<<=1) s += __shfl_xor(s, m);
    const float mean = s * (1.0f/C_);
    float sq = 0.f;
    #pragma unroll
    for (int i=0;i<6;i++){ float d = v[i]-mean; sq += d*d; }
    #pragma unroll
    for (int m=1;m<64;m<<=1) sq += __shfl_xor(sq, m);
    const float rstd = rsqrtf(sq*(1.0f/C_) + 1e-5f);
    #pragma unroll
    for (int i=0;i<6;i++){
        int c = lane + i*64;
        out[(size_t)row*C_ + c] = __float2bfloat16((v[i]-mean)*rstd*g[c] + b[c]);
    }
}

// ---------------- bf16 MFMA GEMM, BK=32, NBUF-buffer single-barrier pipeline ----------------
// (Retained for FC2 only: K=1536 -> 48 steps, prologue amortized, B panel too big for wres.)
#define BK2 32
enum { EPI_QKV=0, EPI_PROJ=1, EPI_FC1=2, EPI_FC2=3 };

template<int EPI, int BMt, int BNt, int NBUF, int MW, int NTH>
__global__ __launch_bounds__(NTH, MW) void gemm_bt(
    const __hip_bfloat16* __restrict__ A,
    const __hip_bfloat16* __restrict__ W,
    const int M, const int N, const int K,
    const float* __restrict__ bias,
    const float* __restrict__ resid,
    const __hip_bfloat16* __restrict__ residb,
    const float* __restrict__ gate,
    float* __restrict__ outf,
    __hip_bfloat16* __restrict__ outb)
{
    constexpr int NWAVE = NTH/64;
    constexpr int NWC   = (BNt >= 128) ? 2 : 1;   // wave-cols
    constexpr int NWR   = NWAVE/NWC;              // wave-rows
    constexpr int WRS   = BMt/NWR;                // output rows per wave
    constexpr int MI    = WRS/16;                 // acc row-frags per wave
    constexpr int APASS = (BMt*BK2*2)/(NTH*16);   // A staging passes
    constexpr int BPASS = (BNt*BK2*2)/(NTH*16);   // B staging passes
    constexpr int LPT   = APASS + BPASS;          // gload_lds per STAGE per thread
    constexpr int RPP   = NTH/4;                  // staging rows per pass
    __shared__ __align__(16) unsigned short As[NBUF][BMt*BK2];
    __shared__ __align__(16) unsigned short Bs[NBUF][BNt*BK2];
    const int t = threadIdx.x;
    const int l = t & 63;
    const int w = t >> 6;
    const int wr = (NWC==2) ? (w >> 1) : w;
    const int wc = (NWC==2) ? (w & 1)  : 0;
    const int nb = N / BNt;
    const int rbX = (M/BMt) >> 3;
    const int X  = blockIdx.x & 7;
    const int j8 = blockIdx.x >> 3;
    const int rb = X*rbX + j8 / nb;
    const int cb = j8 % nb;
    const int srow2 = t >> 2;                          // staging row within pass
    const int sgcol = (((t&3) - ((t>>3)&3)) & 3) * 8;  // chunk-rotation global col
    f32x4 acc[MI][4];
    #pragma unroll
    for (int i=0;i<MI;i++)
        #pragma unroll
        for (int jj=0;jj<4;jj++) acc[i][jj] = (f32x4){0.f,0.f,0.f,0.f};

    const size_t arow0 = (size_t)rb*BMt + srow2;
    const size_t brow0 = (size_t)cb*BNt + srow2;

    auto STAGE = [&](int buf, int k0){
        #pragma unroll
        for (int c=0;c<APASS;c++)
            gload16(A + (arow0 + c*RPP)*K + k0 + sgcol, (char*)&As[buf][0] + c*(NTH*16) + t*16);
        #pragma unroll
        for (int c=0;c<BPASS;c++)
            gload16(W + (brow0 + c*RPP)*K + k0 + sgcol, (char*)&Bs[buf][0] + c*(NTH*16) + t*16);
    };

    auto COMPUTE = [&](int buf){
        const char* as = (const char*)&As[buf][0];
        const char* bs = (const char*)&Bs[buf][0];
        bf16x8 af[MI], bw[4];
        #pragma unroll
        for (int i=0;i<MI;i++){
            const int r = wr*WRS + i*16 + (l&15);
            const int sl = ((l>>4) + ((r>>1)&3)) & 3;
            af[i] = *(const bf16x8*)(as + r*64 + sl*16);
        }
        #pragma unroll
        for (int i=0;i<4;i++){
            const int r = wc*64 + i*16 + (l&15);
            const int sl = ((l>>4) + ((r>>1)&3)) & 3;
            bw[i] = *(const bf16x8*)(bs + r*64 + sl*16);
        }
        #pragma unroll
        for (int mi=0;mi<MI;mi++)
            #pragma unroll
            for (int ni=0;ni<4;ni++)
                acc[mi][ni] = __builtin_amdgcn_mfma_f32_16x16x32_bf16(af[mi], bw[ni], acc[mi][ni], 0,0,0);
    };

    const int nst = K/BK2;
    if constexpr (NBUF==2){
        STAGE(0, 0);
        for (int s=0; s<nst; ++s){
            asm volatile("s_waitcnt vmcnt(0)" ::: "memory");   // only own tile-s loads in flight
            __builtin_amdgcn_s_barrier();
            asm volatile("" ::: "memory");
            if (s+1 < nst) STAGE((s+1)&1, (s+1)*BK2);
            COMPUTE(s&1);
        }
    } else {   // NBUF==3
        STAGE(0, 0);
        STAGE(1, BK2);
        int cur = 0, stb = 2;
        for (int s=0; s<nst; ++s){
            if (s < nst-1){
                if constexpr (LPT==4) asm volatile("s_waitcnt vmcnt(4)" ::: "memory");
                else                  asm volatile("s_waitcnt vmcnt(3)" ::: "memory");
            } else {
                asm volatile("s_waitcnt vmcnt(0)" ::: "memory");
            }
            __builtin_amdgcn_s_barrier();
            asm volatile("" ::: "memory");
            if (s+2 < nst){
                STAGE(stb, (s+2)*BK2);
                stb = (stb+1==3) ? 0 : stb+1;
            }
            COMPUTE(cur);
            cur = (cur+1==3) ? 0 : cur+1;
        }
    }
    // epilogue: C/D layout: col = lane&15, row = (lane>>4)*4 + reg
    const int rowBase = rb*BMt + wr*WRS;
    const int colBase = cb*BNt + wc*64;
    #pragma unroll
    for (int ni=0; ni<4; ni++){
        const int col = colBase + ni*16 + (l&15);
        #pragma unroll
        for (int mi=0; mi<MI; mi++){
            #pragma unroll
            for (int jj=0;jj<4;jj++){
                const int row = rowBase + mi*16 + (l>>4)*4 + jj;
                const float vx = acc[mi][ni][jj];
                size_t idx = (size_t)row*N + col;
                if constexpr (EPI==EPI_PROJ){
                    outb[idx] = __float2bfloat16(resid[idx] + vx + bias[col]);   // x1 in bf16
                } else if constexpr (EPI==EPI_FC2){
                    outf[idx] = bf2f(*((const unsigned short*)residb + idx)) + vx + bias[col];
                } else { // EPI_FC1: GELU (A&S erf) * gate
                    outb[idx] = __float2bfloat16(gelu_f(vx + bias[col]) * gate[col]);
                }
            }
        }
    }
}

// ---------------- R7: A-in-register, B-resident, barrier-free GEMM (all K=384 GEMMs) ----------------
// R6 post-mortem: wres A-bands re-serialize each step (lgkmcnt(0) WAR dance) and RT=2's
// epilogue stores poison counted vmcnt waits (FC1 55.4 -> 61.8). Root insight: the MFMA
// A-fragment is DIRECTLY loadable from row-major global -- lane l wants
// A[r0+i*16+(l&15)][s*32+(l>>4)*8], i.e. 16B at row*768 + s*64 + (l>>4)*16: the wave's 2
// loads consume 32 rows x 64B = 32 FULLY-USED cache lines. So A never touches LDS:
//  - af[3][2] register rotation, 3-step lookahead, fully unrolled (static idx, rule #20).
//  - No manual waitcnts in the loop: compiler inserts exact per-use vmcnt/lgkmcnt; stores
//    can't poison anything; waves fully self-paced, zero K-loop barriers.
//  - LDS = B panel only (64x384 = 48KB, XOR-swizzled byte^=(row&7)<<4 via pre-swizzled
//    source, rule #21) -> 3 blocks/CU = 12 waves/CU (vs wres 8).
// A-side traffic: each col-block re-reads the A panel, but it L2/L3-resides (12.6MB).
template<int EPI, int NCOLS>   // NCOLS: 1536 (FC1) / 1152 (QKV) / 384 (proj)
__global__ __launch_bounds__(256, 3) void gemm_areg(
    const __hip_bfloat16* __restrict__ A,    // [16384, 384]
    const __hip_bfloat16* __restrict__ Wt,   // [NCOLS, 384]
    const float* __restrict__ bias,
    const float* __restrict__ resid,
    const float* __restrict__ gate,
    __hip_bfloat16* __restrict__ outb)
{
    constexpr int NB = NCOLS/64;             // col-blocks
    __shared__ __align__(16) unsigned short Bs[64*384];      // 48KB: whole-K weight panel
    const int t = threadIdx.x;
    const int l = t & 63;
    const int w = t >> 6;
    const int X  = blockIdx.x & 7;
    const int j8 = blockIdx.x >> 3;
    const int rb = X*16 + j8 / NB;           // row-block 0..127 (128 rows each)
    const int cb = j8 % NB;

    // ---- B panel: whole K staged once, 12 gload16/thread, pre-swizzled source ----
    #pragma unroll
    for (int j=0;j<12;j++){
        const int L     = (w*12 + j)*1024 + l*16;       // linear LDS byte (gload_lds HW rule)
        const int row   = L / 768;                      // B row 0..63
        const int cbyte = L - row*768;
        const int scol  = (cbyte ^ ((row&7)<<4)) >> 1;  // inverse-swizzled source col (elems)
        gload16(Wt + (size_t)(cb*64 + row)*384 + scol, (char*)&Bs[0] + L);
    }

    // ---- A fragments: direct global->VGPR, 3-step register rotation ----
    // lane l, frag i, step s: A[rb*128 + w*32 + i*16 + (l&15)][s*32 + (l>>4)*8]
    const unsigned short* Ap = (const unsigned short*)A
        + ((size_t)rb*128 + w*32 + (l&15))*384 + (l>>4)*8;
    bf16x8 af[3][2];
    #pragma unroll
    for (int p=0;p<3;p++)
        #pragma unroll
        for (int i=0;i<2;i++)
            af[p][i] = *(const bf16x8*)(Ap + (size_t)i*16*384 + p*32);

    asm volatile("s_waitcnt vmcnt(0)" ::: "memory");    // B panel (and prologue A) landed
    __builtin_amdgcn_s_barrier();                        // the ONLY barrier

    f32x4 acc[2][4];
    #pragma unroll
    for (int i=0;i<2;i++)
        #pragma unroll
        for (int jj=0;jj<4;jj++) acc[i][jj] = (f32x4){0.f,0.f,0.f,0.f};

    #pragma unroll
    for (int s=0; s<12; ++s){
        bf16x8 bw[4];
        #pragma unroll
        for (int i=0;i<4;i++){
            const int r = i*16 + (l&15);                  // B row (output col) 0..63
            bw[i] = *(const bf16x8*)((const char*)&Bs[0] + r*768
                         + ((s*64 + (l>>4)*16) ^ ((r&7)<<4)));
        }
        #pragma unroll
        for (int ni=0;ni<4;ni++){
            acc[0][ni] = __builtin_amdgcn_mfma_f32_16x16x32_bf16(af[s%3][0], bw[ni], acc[0][ni], 0,0,0);
            acc[1][ni] = __builtin_amdgcn_mfma_f32_16x16x32_bf16(af[s%3][1], bw[ni], acc[1][ni], 0,0,0);
        }
        if (s+3 < 12){
            #pragma unroll
            for (int i=0;i<2;i++)
                af[(s+3)%3][i] = *(const bf16x8*)(Ap + (size_t)i*16*384 + (s+3)*32);
        }
    }

    // ---- epilogue ----
    const int rowBase = rb*128 + w*32;
    if constexpr (EPI==EPI_QKV){
        // scatter: Q,K -> [p][B][H][N][64]; V (p==2) -> [B][H][64][N] (transposed)
        unsigned short* ob = (unsigned short*)outb;
        #pragma unroll
        for (int ni=0; ni<4; ni++){
            const int col = cb*64 + ni*16 + (l&15);
            const int p = col/384, rem = col - p*384;
            const int hh = rem>>6, d = rem&63;
            #pragma unroll
            for (int mi=0; mi<2; mi++){
                const int row0 = rowBase + mi*16 + (l>>4)*4;
                const int bb = row0>>10, n = row0&1023;
                if (p==2){
                    u16x4 pk;
                    #pragma unroll
                    for (int jj=0;jj<4;jj++) pk[jj] = f2bf(acc[mi][ni][jj]);
                    *(u16x4*)(ob + (size_t)2*6291456 + ((size_t)(bb*H_+hh)*64 + d)*1024 + n) = pk;
                } else {
                    #pragma unroll
                    for (int jj=0;jj<4;jj++)
                        ob[(((size_t)((p*16+bb)*6+hh))<<16) + ((size_t)(n+jj)<<6) + d] = f2bf(acc[mi][ni][jj]);
                }
            }
        }
    } else {
        #pragma unroll
        for (int ni=0; ni<4; ni++){
            const int col = cb*64 + ni*16 + (l&15);
            #pragma unroll
            for (int mi=0; mi<2; mi++){
                #pragma unroll
                for (int jj=0;jj<4;jj++){
                    const int row = rowBase + mi*16 + (l>>4)*4 + jj;
                    const size_t idx = (size_t)row*NCOLS + col;
                    if constexpr (EPI==EPI_PROJ){
                        outb[idx] = __float2bfloat16(resid[idx] + acc[mi][ni][jj] + bias[col]);
                    } else { // EPI_FC1
                        outb[idx] = __float2bfloat16(gelu_f(acc[mi][ni][jj] + bias[col]) * gate[col]);
                    }
                }
            }
        }
    }
}

// ---------------- MFMA flash attention, 3-buffer single-barrier pipeline (R12-best) ----------------
// QBLK=128 (grid 768): 4 waves, wave w owns 32 q-rows. In-register P via swapped QK^T
// + phys_k permutation (lane-local k-ownership -> P packed via v_cvt_pk_bf16_f32).
// Per-lane rs_part denominators, reduced once after the loop. VGPR 72 -> 3 blocks/CU
// (register cliff: do NOT add live state). exp via raw v_exp_f32 (R12 win).
__global__ __launch_bounds__(256) void attn_mfma(
    const __hip_bfloat16* __restrict__ qg,   // [B,H,N,64]
    const __hip_bfloat16* __restrict__ kg,   // [B,H,N,64]
    const __hip_bfloat16* __restrict__ vtg,  // [B,H,64,N]
    const float* __restrict__ gate_h,
    __hip_bfloat16* __restrict__ og)         // [B,N,C]
{
    __shared__ __align__(16) unsigned short Ks [3][64*64];
    __shared__ __align__(16) unsigned short Vts[3][64*64];
    const int t = threadIdx.x;
    const int l = t & 63;
    const int w = t >> 6;
    // XCD swizzle: 96 bh over 8 XCDs = 12 bh/XCD, 8 q-tiles each contiguous
    const int X  = blockIdx.x & 7;
    const int j8 = blockIdx.x >> 3;          // 0..95
    const int bh = X*12 + (j8 >> 3);
    const int n0 = (j8 & 7) * 128;
    const int h  = bh % H_;
    const int b  = bh / H_;
    const unsigned short* qp  = (const unsigned short*)qg  + ((size_t)bh*N_ + n0 + w*32)*64;
    const unsigned short* kp  = (const unsigned short*)kg  + (size_t)bh*N_*64;
    const unsigned short* vtp = (const unsigned short*)vtg + (size_t)bh*64*N_;

    // Q fragments (B-operand layout), scale*log2e folded in
    bf16x8 qf[2][2];
    #pragma unroll
    for (int mt=0;mt<2;mt++)
        #pragma unroll
        for (int dc=0;dc<2;dc++){
            u16x8 raw = *(const u16x8*)(qp + ((size_t)(mt*16 + (l&15)))*64 + dc*32 + (l>>4)*8);
            u16x8 sc;
            #pragma unroll
            for (int j=0;j<8;j++) sc[j] = f2bf(bf2f(raw[j]) * 0.1803368801111244f);
            qf[mt][dc] = __builtin_bit_cast(bf16x8, sc);
        }

    // pre-hoisted ds_read byte offsets (lane-dependent, kt-invariant)
    int qk_off[4][2], pv_off[2][4];
    #pragma unroll
    for (int t4=0;t4<4;t4++){
        const int i    = l & 15;
        const int row  = 8*(i>>2) + (i&3) + 4*(t4&1) + 32*(t4>>1);   // phys_k(t4, i)
        const int swzr = (row&3) | (((row>>3)&1)<<2);
        #pragma unroll
        for (int dc=0;dc<2;dc++)
            qk_off[t4][dc] = row*128 + ((dc*64 + (l>>4)*16) ^ (swzr<<4));
    }
    #pragma unroll
    for (int nt=0;nt<4;nt++){
        const int row  = nt*16 + (l&15);
        const int swzr = (row&3) | (((row>>3)&1)<<2);
        #pragma unroll
        for (int kc=0;kc<2;kc++)
            pv_off[kc][nt] = row*128 + ((kc*64 + (l>>4)*16) ^ (swzr<<4));
    }

    const int sr  = t >> 3;        // staging row 0..31 (and +32)
    const int sce = (t & 7) * 8;   // staging col (elements) before swizzle

    auto STAGE = [&](int buf, int kt){
        #pragma unroll
        for (int c=0;c<2;c++){
            const int r    = sr + c*32;
            const int swzr = (r&3) | (((r>>3)&1)<<2);
            const int col  = sce ^ (swzr<<3);           // inverse-swizzled global col
            gload16(kp  + ((size_t)(kt*64 + r))*64 + col, (char*)&Ks [buf][0] + (c*256 + t)*16);
            gload16(vtp + (size_t)r*N_ + kt*64 + col,     (char*)&Vts[buf][0] + (c*256 + t)*16);
        }
    };

    f32x4 o_acc[2][4];
    #pragma unroll
    for (int i=0;i<2;i++)
        #pragma unroll
        for (int jj=0;jj<4;jj++) o_acc[i][jj] = (f32x4){0.f,0.f,0.f,0.f};
    float rs_part[2] = {0.f, 0.f};   // per-lane partial denominators (k is lane-local)

    STAGE(0, 0);
    STAGE(1, 1);
    int cur = 0, stb = 2;
    for (int kt=0; kt<16; kt++){
        if (kt < 15) asm volatile("s_waitcnt vmcnt(4)" ::: "memory");  // own tile done; next in flight
        else         asm volatile("s_waitcnt vmcnt(0)" ::: "memory");
        __builtin_amdgcn_s_barrier();
        asm volatile("" ::: "memory");
        if (kt < 14){
            STAGE(stb, kt+2);
            stb = (stb+1==3) ? 0 : stb+1;
        }
        const char* ks = (const char*)&Ks[cur][0];
        const char* vs = (const char*)&Vts[cur][0];

        // QK^T (swapped): A=K (permuted rows), B=Q
        f32x4 s_acc[4][2];
        #pragma unroll
        for (int i=0;i<4;i++)
            #pragma unroll
            for (int jj=0;jj<2;jj++) s_acc[i][jj] = (f32x4){0.f,0.f,0.f,0.f};
        #pragma unroll
        for (int t4=0;t4<4;t4++)
            #pragma unroll
            for (int dc=0;dc<2;dc++){
                bf16x8 kf = *(const bf16x8*)(ks + qk_off[t4][dc]);
                #pragma unroll
                for (int mt=0;mt<2;mt++)
                    s_acc[t4][mt] = __builtin_amdgcn_mfma_f32_16x16x32_bf16(kf, qf[mt][dc], s_acc[t4][mt], 0,0,0);
            }
        // exp via raw v_exp_f32 (scale pre-folded; scores bounded) + per-lane partials
        #pragma unroll
        for (int mt=0;mt<2;mt++){
            float acc_s = 0.f;
            #pragma unroll
            for (int t4=0;t4<4;t4++){
                #pragma unroll
                for (int jj=0;jj<4;jj++){
                    float e = fast_exp2(s_acc[t4][mt][jj]);
                    s_acc[t4][mt][jj] = e;
                    acc_s += e;
                }
            }
            rs_part[mt] += acc_s;
        }
        // PV: P-fragments packed in-register (lane-local k-ownership)
        #pragma unroll
        for (int kc=0;kc<2;kc++){
            union { unsigned int u[4]; bf16x8 v; } pu[2];
            #pragma unroll
            for (int mt=0;mt<2;mt++){
                pu[mt].u[0] = cvt_pk_bf16(s_acc[2*kc  ][mt][0], s_acc[2*kc  ][mt][1]);
                pu[mt].u[1] = cvt_pk_bf16(s_acc[2*kc  ][mt][2], s_acc[2*kc  ][mt][3]);
                pu[mt].u[2] = cvt_pk_bf16(s_acc[2*kc+1][mt][0], s_acc[2*kc+1][mt][1]);
                pu[mt].u[3] = cvt_pk_bf16(s_acc[2*kc+1][mt][2], s_acc[2*kc+1][mt][3]);
            }
            #pragma unroll
            for (int nt=0;nt<4;nt++){
                bf16x8 vf = *(const bf16x8*)(vs + pv_off[kc][nt]);
                #pragma unroll
                for (int mt=0;mt<2;mt++)
                    o_acc[mt][nt] = __builtin_amdgcn_mfma_f32_16x16x32_bf16(pu[mt].v, vf, o_acc[mt][nt], 0,0,0);
            }
        }
        cur = (cur+1==3) ? 0 : cur+1;
    }
    // final denominator: reduce across the 4 lane-groups, then broadcast to output layout
    float rowsum[2];
    #pragma unroll
    for (int mt=0;mt<2;mt++){
        float rs = rs_part[mt];
        rs += __shfl_xor(rs, 16);
        rs += __shfl_xor(rs, 32);
        rowsum[mt] = rs;           // full sum for q = mt*16 + (l&15), uniform across groups
    }
    const float gh = gate_h[h];
    float inv[2][4];
    #pragma unroll
    for (int mt=0;mt<2;mt++)
        #pragma unroll
        for (int r=0;r<4;r++)
            inv[mt][r] = gh / __shfl(rowsum[mt], (l>>4)*4 + r, 16);
    // epilogue: normalize, gate, write O[b][n][h*64+d]
    unsigned short* op = (unsigned short*)og + ((size_t)b*N_ + n0 + w*32)*C_ + h*64;
    #pragma unroll
    for (int mt=0;mt<2;mt++){
        #pragma unroll
        for (int r=0;r<4;r++){
            const int n = mt*16 + (l>>4)*4 + r;
            #pragma unroll
            for (int nt=0;nt<4;nt++)
                op[(size_t)n*C_ + nt*16 + (l&15)] = f2bf(o_acc[mt][nt][r]*inv[mt][r]);
        }
    }
}

// ---------------- launch ----------------
extern "C" void kernel_launch(void* const* d_in, const int* in_sizes, int n_in,
                              void* d_out, int out_size, void* d_ws, size_t ws_size,
                              hipStream_t stream)
{
    const float* x     = (const float*)d_in[0];
    const float* ln1g  = (const float*)d_in[1];
    const float* ln1b  = (const float*)d_in[2];
    const float* qkvw  = (const float*)d_in[3];
    const float* projw = (const float*)d_in[4];
    const float* projb = (const float*)d_in[5];
    const float* gateh = (const float*)d_in[6];
    const float* ln2g  = (const float*)d_in[7];
    const float* ln2b  = (const float*)d_in[8];
    const float* fc1w  = (const float*)d_in[9];
    const float* fc1b  = (const float*)d_in[10];
    const float* fc2w  = (const float*)d_in[11];
    const float* fc2b  = (const float*)d_in[12];
    const float* gatem = (const float*)d_in[13];
    float* out = (float*)d_out;

    char* ws = (char*)d_ws;
    __hip_bfloat16* h_buf = (__hip_bfloat16*)(ws + 0);          // 12.58MB  (h / h2)
    __hip_bfloat16* qkv   = (__hip_bfloat16*)(ws + 12582912);   // 37.75MB  (q,k,v^T)
    __hip_bfloat16* q_buf = qkv;
    __hip_bfloat16* k_buf = qkv + 6291456;
    __hip_bfloat16* vt_buf= qkv + 2*6291456;
    __hip_bfloat16* o_buf = (__hip_bfloat16*)(ws + 50331648);   // 12.58MB
    __hip_bfloat16* m_buf = (__hip_bfloat16*)(ws + 12582912);   // 50.33MB (reuses dead qkv+o)
    __hip_bfloat16* x1b   = (__hip_bfloat16*)(ws + 62914560);   // 12.58MB (bf16 residual)
    __hip_bfloat16* wqkv  = (__hip_bfloat16*)(ws + 88080384);
    __hip_bfloat16* wproj = (__hip_bfloat16*)(ws + 88965120);
    __hip_bfloat16* wfc1  = (__hip_bfloat16*)(ws + 89260032);
    __hip_bfloat16* wfc2  = (__hip_bfloat16*)(ws + 90439680);

    // LN1 + all weight converts, one launch (independent memory-bound tasks)
    ln1_cvt_kernel<<<5120, 256, 0, stream>>>(x, ln1g, ln1b, h_buf,
                                             qkvw, wqkv, 1152*384,
                                             projw, wproj, 384*384,
                                             fc1w, wfc1, 1536*384,
                                             fc2w, wfc2, 384*1536);

    // R7: all K=384 GEMMs -> A-in-register barrier-free structure; FC2 stays gemm_bt
    gemm_areg<EPI_QKV,1152><<<2304, 256, 0, stream>>>(h_buf, wqkv, nullptr, nullptr, nullptr, qkv);
    attn_mfma<<<768, 256, 0, stream>>>(q_buf, k_buf, vt_buf, gateh, o_buf);
    gemm_areg<EPI_PROJ,384><<<768, 256, 0, stream>>>(o_buf, wproj, projb, x, nullptr, x1b);
    ln_kernel<__hip_bfloat16><<<4096, 256, 0, stream>>>(x1b, ln2g, ln2b, h_buf);
    gemm_areg<EPI_FC1,1536><<<3072, 256, 0, stream>>>(h_buf, wfc1, fc1b, nullptr, gatem, m_buf);
    gemm_bt<EPI_FC2,64,128,3,1,256><<<768, 256, 0, stream>>>(m_buf, wfc2, R_, 384, 1536,
                                                             fc2b, nullptr, x1b, nullptr, out, nullptr);
}

// Round 8
// 174.406 us; speedup vs baseline: 1.1096x; 1.1096x over previous
//
#include <hip/hip_runtime.h>
#include <hip/hip_bf16.h>
#include <cstdint>
#include <cstddef>

#define B_   16
#define N_   1024
#define C_   384
#define H_   6
#define DFF_ 1536
#define R_   16384   // B_*N_

typedef __attribute__((ext_vector_type(8))) __bf16 bf16x8;
typedef __attribute__((ext_vector_type(4))) float  f32x4;
typedef __attribute__((ext_vector_type(8))) unsigned short u16x8;
typedef __attribute__((ext_vector_type(4))) unsigned short u16x4;

__device__ __forceinline__ float bf2f(unsigned short u){
    unsigned int x = ((unsigned int)u) << 16;
    return __builtin_bit_cast(float, x);
}
__device__ __forceinline__ unsigned short f2bf(float f){
    return __builtin_bit_cast(unsigned short, __float2bfloat16(f));
}
__device__ __forceinline__ unsigned int cvt_pk_bf16(float a, float b){
    unsigned int r;
    asm("v_cvt_pk_bf16_f32 %0, %1, %2" : "=v"(r) : "v"(a), "v"(b));
    return r;   // lo = bf16(a), hi = bf16(b)
}
// raw v_exp_f32 (2^x). Args provably in [-45,0] -> no OCML range/denorm fixup needed.
__device__ __forceinline__ float fast_exp2(float x){
    float r;
    asm("v_exp_f32 %0, %1" : "=v"(r) : "v"(x));
    return r;
}
__device__ __forceinline__ void gload16(const void* g, void* l){
    __builtin_amdgcn_global_load_lds(
        (const __attribute__((address_space(1))) unsigned int*)g,
        (__attribute__((address_space(3))) unsigned int*)l, 16, 0, 0);
}
// exact-GELU via Abramowitz-Stegun 7.1.25 erf approx (|err| <= 2.5e-5)
__device__ __forceinline__ float gelu_f(float u){
    float z  = fabsf(u) * 0.70710678118654752f;
    float t  = __builtin_amdgcn_rcpf(1.0f + 0.47047f*z);
    float e  = __expf(-z*z);
    float p  = t*(0.3480242f + t*(-0.0958798f + t*0.7478556f));
    float er = 1.0f - p*e;                       // erf(z), z>=0
    return 0.5f*u*(1.0f + copysignf(er, u));
}
__device__ __forceinline__ float ldv(const float* p, size_t i){ return p[i]; }
__device__ __forceinline__ float ldv(const __hip_bfloat16* p, size_t i){ return __bfloat162float(p[i]); }

// ---------------- LN1 + all-weight fp32->bf16 convert, one launch ----------------
__global__ __launch_bounds__(256) void ln1_cvt_kernel(
    const float* __restrict__ x, const float* __restrict__ g,
    const float* __restrict__ b, __hip_bfloat16* __restrict__ out,
    const float* __restrict__ i0, __hip_bfloat16* __restrict__ o0, int n0,
    const float* __restrict__ i1, __hip_bfloat16* __restrict__ o1, int n1,
    const float* __restrict__ i2, __hip_bfloat16* __restrict__ o2, int n2,
    const float* __restrict__ i3, __hip_bfloat16* __restrict__ o3, int n3)
{
    if (blockIdx.x < 4096){
        const int lane = threadIdx.x & 63;
        const int wave = threadIdx.x >> 6;
        const int row  = blockIdx.x*4 + wave;
        const float* xr = x + (size_t)row*C_;
        float v[6];
        float s = 0.f;
        #pragma unroll
        for (int i=0;i<6;i++){ v[i] = xr[lane + i*64]; s += v[i]; }
        #pragma unroll
        for (int m=1;m<64;m<<=1) s += __shfl_xor(s, m);
        const float mean = s * (1.0f/C_);
        float sq = 0.f;
        #pragma unroll
        for (int i=0;i<6;i++){ float d = v[i]-mean; sq += d*d; }
        #pragma unroll
        for (int m=1;m<64;m<<=1) sq += __shfl_xor(sq, m);
        const float rstd = rsqrtf(sq*(1.0f/C_) + 1e-5f);
        #pragma unroll
        for (int i=0;i<6;i++){
            int c = lane + i*64;
            out[(size_t)row*C_ + c] = __float2bfloat16((v[i]-mean)*rstd*g[c] + b[c]);
        }
    } else {
        const int total = n0+n1+n2+n3;
        for (int i = (blockIdx.x-4096)*blockDim.x + threadIdx.x; i < total; i += 1024*blockDim.x){
            int k = i;
            if (k < n0){ o0[k] = __float2bfloat16(i0[k]); continue; }
            k -= n0;
            if (k < n1){ o1[k] = __float2bfloat16(i1[k]); continue; }
            k -= n1;
            if (k < n2){ o2[k] = __float2bfloat16(i2[k]); continue; }
            k -= n2;
            o3[k] = __float2bfloat16(i3[k]);
        }
    }
}

// ---------------- LayerNorm: (fp32|bf16) in -> bf16 out ----------------
template<typename T>
__global__ __launch_bounds__(256) void ln_kernel(
    const T* __restrict__ x, const float* __restrict__ g,
    const float* __restrict__ b, __hip_bfloat16* __restrict__ out)
{
    const int lane = threadIdx.x & 63;
    const int wave = threadIdx.x >> 6;
    const int row  = blockIdx.x*4 + wave;
    const T* xr = x + (size_t)row*C_;
    float v[6];
    float s = 0.f;
    #pragma unroll
    for (int i=0;i<6;i++){ v[i] = ldv(xr, lane + i*64); s += v[i]; }
    #pragma unroll
    for (int m=1;m<64;m<<=1) s += __shfl_xor(s, m);
    const float mean = s * (1.0f/C_);
    float sq = 0.f;
    #pragma unroll
    for (int i=0;i<6;i++){ float d = v[i]-mean; sq += d*d; }
    #pragma unroll
    for (int m=1;m<64;m<<=1) sq += __shfl_xor(sq, m);
    const float rstd = rsqrtf(sq*(1.0f/C_) + 1e-5f);
    #pragma unroll
    for (int i=0;i<6;i++){
        int c = lane + i*64;
        out[(size_t)row*C_ + c] = __float2bfloat16((v[i]-mean)*rstd*g[c] + b[c]);
    }
}

// ---------------- bf16 MFMA GEMM, BK=32, NBUF-buffer single-barrier pipeline ----------------
// (Retained for FC2 only: K=1536 -> 48 steps, prologue amortized, B panel too big for wres.)
#define BK2 32
enum { EPI_QKV=0, EPI_PROJ=1, EPI_FC1=2, EPI_FC2=3 };

template<int EPI, int BMt, int BNt, int NBUF, int MW, int NTH>
__global__ __launch_bounds__(NTH, MW) void gemm_bt(
    const __hip_bfloat16* __restrict__ A,
    const __hip_bfloat16* __restrict__ W,
    const int M, const int N, const int K,
    const float* __restrict__ bias,
    const float* __restrict__ resid,
    const __hip_bfloat16* __restrict__ residb,
    const float* __restrict__ gate,
    float* __restrict__ outf,
    __hip_bfloat16* __restrict__ outb)
{
    constexpr int NWAVE = NTH/64;
    constexpr int NWC   = (BNt >= 128) ? 2 : 1;   // wave-cols
    constexpr int NWR   = NWAVE/NWC;              // wave-rows
    constexpr int WRS   = BMt/NWR;                // output rows per wave
    constexpr int MI    = WRS/16;                 // acc row-frags per wave
    constexpr int APASS = (BMt*BK2*2)/(NTH*16);   // A staging passes
    constexpr int BPASS = (BNt*BK2*2)/(NTH*16);   // B staging passes
    constexpr int LPT   = APASS + BPASS;          // gload_lds per STAGE per thread
    constexpr int RPP   = NTH/4;                  // staging rows per pass
    __shared__ __align__(16) unsigned short As[NBUF][BMt*BK2];
    __shared__ __align__(16) unsigned short Bs[NBUF][BNt*BK2];
    const int t = threadIdx.x;
    const int l = t & 63;
    const int w = t >> 6;
    const int wr = (NWC==2) ? (w >> 1) : w;
    const int wc = (NWC==2) ? (w & 1)  : 0;
    const int nb = N / BNt;
    const int rbX = (M/BMt) >> 3;
    const int X  = blockIdx.x & 7;
    const int j8 = blockIdx.x >> 3;
    const int rb = X*rbX + j8 / nb;
    const int cb = j8 % nb;
    const int srow2 = t >> 2;                          // staging row within pass
    const int sgcol = (((t&3) - ((t>>3)&3)) & 3) * 8;  // chunk-rotation global col
    f32x4 acc[MI][4];
    #pragma unroll
    for (int i=0;i<MI;i++)
        #pragma unroll
        for (int jj=0;jj<4;jj++) acc[i][jj] = (f32x4){0.f,0.f,0.f,0.f};

    const size_t arow0 = (size_t)rb*BMt + srow2;
    const size_t brow0 = (size_t)cb*BNt + srow2;

    auto STAGE = [&](int buf, int k0){
        #pragma unroll
        for (int c=0;c<APASS;c++)
            gload16(A + (arow0 + c*RPP)*K + k0 + sgcol, (char*)&As[buf][0] + c*(NTH*16) + t*16);
        #pragma unroll
        for (int c=0;c<BPASS;c++)
            gload16(W + (brow0 + c*RPP)*K + k0 + sgcol, (char*)&Bs[buf][0] + c*(NTH*16) + t*16);
    };

    auto COMPUTE = [&](int buf){
        const char* as = (const char*)&As[buf][0];
        const char* bs = (const char*)&Bs[buf][0];
        bf16x8 af[MI], bw[4];
        #pragma unroll
        for (int i=0;i<MI;i++){
            const int r = wr*WRS + i*16 + (l&15);
            const int sl = ((l>>4) + ((r>>1)&3)) & 3;
            af[i] = *(const bf16x8*)(as + r*64 + sl*16);
        }
        #pragma unroll
        for (int i=0;i<4;i++){
            const int r = wc*64 + i*16 + (l&15);
            const int sl = ((l>>4) + ((r>>1)&3)) & 3;
            bw[i] = *(const bf16x8*)(bs + r*64 + sl*16);
        }
        #pragma unroll
        for (int mi=0;mi<MI;mi++)
            #pragma unroll
            for (int ni=0;ni<4;ni++)
                acc[mi][ni] = __builtin_amdgcn_mfma_f32_16x16x32_bf16(af[mi], bw[ni], acc[mi][ni], 0,0,0);
    };

    const int nst = K/BK2;
    if constexpr (NBUF==2){
        STAGE(0, 0);
        for (int s=0; s<nst; ++s){
            asm volatile("s_waitcnt vmcnt(0)" ::: "memory");   // only own tile-s loads in flight
            __builtin_amdgcn_s_barrier();
            asm volatile("" ::: "memory");
            if (s+1 < nst) STAGE((s+1)&1, (s+1)*BK2);
            COMPUTE(s&1);
        }
    } else {   // NBUF==3
        STAGE(0, 0);
        STAGE(1, BK2);
        int cur = 0, stb = 2;
        for (int s=0; s<nst; ++s){
            if (s < nst-1){
                if constexpr (LPT==4) asm volatile("s_waitcnt vmcnt(4)" ::: "memory");
                else                  asm volatile("s_waitcnt vmcnt(3)" ::: "memory");
            } else {
                asm volatile("s_waitcnt vmcnt(0)" ::: "memory");
            }
            __builtin_amdgcn_s_barrier();
            asm volatile("" ::: "memory");
            if (s+2 < nst){
                STAGE(stb, (s+2)*BK2);
                stb = (stb+1==3) ? 0 : stb+1;
            }
            COMPUTE(cur);
            cur = (cur+1==3) ? 0 : cur+1;
        }
    }
    // epilogue: C/D layout: col = lane&15, row = (lane>>4)*4 + reg
    const int rowBase = rb*BMt + wr*WRS;
    const int colBase = cb*BNt + wc*64;
    #pragma unroll
    for (int ni=0; ni<4; ni++){
        const int col = colBase + ni*16 + (l&15);
        #pragma unroll
        for (int mi=0; mi<MI; mi++){
            #pragma unroll
            for (int jj=0;jj<4;jj++){
                const int row = rowBase + mi*16 + (l>>4)*4 + jj;
                const float vx = acc[mi][ni][jj];
                size_t idx = (size_t)row*N + col;
                if constexpr (EPI==EPI_PROJ){
                    outb[idx] = __float2bfloat16(resid[idx] + vx + bias[col]);   // x1 in bf16
                } else if constexpr (EPI==EPI_FC2){
                    outf[idx] = bf2f(*((const unsigned short*)residb + idx)) + vx + bias[col];
                } else { // EPI_FC1: GELU (A&S erf) * gate
                    outb[idx] = __float2bfloat16(gelu_f(vx + bias[col]) * gate[col]);
                }
            }
        }
    }
}

// ---------------- R8: weight-resident barrier-free GEMM, 4-band deep lead, RT=1 ----------------
// Consolidation of the measured-positive pieces only:
//  - wres structure (R5: FC1 55.4, session-best): B panel LDS-resident staged once
//    (single barrier), A in wave-private LDS bands, waves self-paced by own vmcnt,
//    ZERO K-loop barriers.
//  - 4th A-band (deep lead): steady vmcnt(4) = 2 bands in flight = 2-step (~600-1000cy)
//    lead vs R5's 1-step. (R6 tried this confounded with RT=2; now clean.)
//  - RT=1: epilogue runs after the loop -> stores can never poison a counted vmcnt
//    (R6's RT=2 regression, FC1 55.4->61.8, is thereby removed).
// LDS = 48KB (B) + 32KB (4 bands) = 80KB -> 2 blocks/CU, 8 self-paced waves/CU.
// Applied to all K=384 GEMMs (FC1 / QKV / proj). FC2 (K=1536) stays gemm_bt.
// FC1 ledger: 72.9 -> 68.6 -> 59.2 -> 59.5 -> 55.4(wres) -> 61.8(RT2) -> 63.2(areg) -> ?
template<int EPI, int NCOLS>   // NCOLS: 1536 (FC1) / 1152 (QKV) / 384 (proj)
__global__ __launch_bounds__(256, 2) void gemm_wres4(
    const __hip_bfloat16* __restrict__ A,    // [16384, 384]
    const __hip_bfloat16* __restrict__ Wt,   // [NCOLS, 384]
    const float* __restrict__ bias,
    const float* __restrict__ resid,
    const float* __restrict__ gate,
    __hip_bfloat16* __restrict__ outb)
{
    constexpr int NB = NCOLS/64;             // col-blocks
    __shared__ __align__(16) unsigned short As[4][128*32];   // 32KB: 4 bands, wave-private 32rx32k
    __shared__ __align__(16) unsigned short Bs[64*384];      // 48KB: whole-K weight panel
    const int t = threadIdx.x;
    const int l = t & 63;
    const int w = t >> 6;
    const int X  = blockIdx.x & 7;
    const int j8 = blockIdx.x >> 3;
    const int rb = X*16 + j8 / NB;           // row-block 0..127 (128 rows each)
    const int cb = j8 % NB;

    // ---- B panel: whole K staged once, 12 gload16/thread, pre-swizzled source ----
    #pragma unroll
    for (int j=0;j<12;j++){
        const int L     = (w*12 + j)*1024 + l*16;       // linear LDS byte (gload_lds HW rule)
        const int row   = L / 768;                      // B row 0..63
        const int cbyte = L - row*768;
        const int scol  = (cbyte ^ ((row&7)<<4)) >> 1;  // inverse-swizzled source col (elems)
        gload16(Wt + (size_t)(cb*64 + row)*384 + scol, (char*)&Bs[0] + L);
    }
    // ---- A bands: wave-private, 2 gload16 per band (32 rows x 32 K) ----
    const int sgcol = (((l&3) - ((l>>3)&3)) & 3) * 8;
    const size_t arow0 = (size_t)rb*128 + w*32 + (l>>2);
    auto STAGEA = [&](int g){
        #pragma unroll
        for (int c=0;c<2;c++)
            gload16(A + (arow0 + c*16)*384 + g*32 + sgcol,
                    (char*)&As[g&3][0] + w*2048 + c*1024 + l*16);
    };
    STAGEA(0); STAGEA(1); STAGEA(2);
    asm volatile("s_waitcnt vmcnt(6)" ::: "memory");    // 12 B loads drained; 3 bands in flight
    __builtin_amdgcn_s_barrier();                        // the ONLY barrier

    f32x4 acc[2][4];
    #pragma unroll
    for (int i=0;i<2;i++)
        #pragma unroll
        for (int jj=0;jj<4;jj++) acc[i][jj] = (f32x4){0.f,0.f,0.f,0.f};

    #pragma unroll
    for (int s=0; s<12; ++s){
        if (s < 10)      asm volatile("s_waitcnt vmcnt(4)" ::: "memory");  // band s ready; 2 newer in flight
        else if (s == 10) asm volatile("s_waitcnt vmcnt(2)" ::: "memory");
        else              asm volatile("s_waitcnt vmcnt(0)" ::: "memory");
        const char* as = (const char*)&As[s&3][0] + w*2048;
        bf16x8 af[2], bw[4];
        #pragma unroll
        for (int i=0;i<2;i++){
            const int r  = i*16 + (l&15);                 // local band row 0..31
            const int sl = ((l>>4) + ((r>>1)&3)) & 3;
            af[i] = *(const bf16x8*)(as + r*64 + sl*16);
        }
        #pragma unroll
        for (int i=0;i<4;i++){
            const int r = i*16 + (l&15);                  // B row (output col) 0..63
            bw[i] = *(const bf16x8*)((const char*)&Bs[0] + r*768
                         + ((s*64 + (l>>4)*16) ^ ((r&7)<<4)));
        }
        #pragma unroll
        for (int mi=0;mi<2;mi++)
            #pragma unroll
            for (int ni=0;ni<4;ni++)
                acc[mi][ni] = __builtin_amdgcn_mfma_f32_16x16x32_bf16(af[mi], bw[ni], acc[mi][ni], 0,0,0);
        asm volatile("s_waitcnt lgkmcnt(0)" ::: "memory");  // own ds_reads retired before band overwrite
        if (s+3 < 12) STAGEA(s+3);                          // writes band (s-1)&3, reads retired at s-1
    }

    // ---- epilogue (after loop: stores cannot poison counted waits) ----
    const int rowBase = rb*128 + w*32;
    if constexpr (EPI==EPI_QKV){
        // scatter: Q,K -> [p][B][H][N][64]; V (p==2) -> [B][H][64][N] (transposed)
        unsigned short* ob = (unsigned short*)outb;
        #pragma unroll
        for (int ni=0; ni<4; ni++){
            const int col = cb*64 + ni*16 + (l&15);
            const int p = col/384, rem = col - p*384;
            const int hh = rem>>6, d = rem&63;
            #pragma unroll
            for (int mi=0; mi<2; mi++){
                const int row0 = rowBase + mi*16 + (l>>4)*4;
                const int bb = row0>>10, n = row0&1023;
                if (p==2){
                    u16x4 pk;
                    #pragma unroll
                    for (int jj=0;jj<4;jj++) pk[jj] = f2bf(acc[mi][ni][jj]);
                    *(u16x4*)(ob + (size_t)2*6291456 + ((size_t)(bb*H_+hh)*64 + d)*1024 + n) = pk;
                } else {
                    #pragma unroll
                    for (int jj=0;jj<4;jj++)
                        ob[(((size_t)((p*16+bb)*6+hh))<<16) + ((size_t)(n+jj)<<6) + d] = f2bf(acc[mi][ni][jj]);
                }
            }
        }
    } else {
        #pragma unroll
        for (int ni=0; ni<4; ni++){
            const int col = cb*64 + ni*16 + (l&15);
            #pragma unroll
            for (int mi=0; mi<2; mi++){
                #pragma unroll
                for (int jj=0;jj<4;jj++){
                    const int row = rowBase + mi*16 + (l>>4)*4 + jj;
                    const size_t idx = (size_t)row*NCOLS + col;
                    if constexpr (EPI==EPI_PROJ){
                        outb[idx] = __float2bfloat16(resid[idx] + acc[mi][ni][jj] + bias[col]);
                    } else { // EPI_FC1
                        outb[idx] = __float2bfloat16(gelu_f(acc[mi][ni][jj] + bias[col]) * gate[col]);
                    }
                }
            }
        }
    }
}

// ---------------- MFMA flash attention, 3-buffer single-barrier pipeline (R12-best) ----------------
// QBLK=128 (grid 768): 4 waves, wave w owns 32 q-rows. In-register P via swapped QK^T
// + phys_k permutation (lane-local k-ownership -> P packed via v_cvt_pk_bf16_f32).
// Per-lane rs_part denominators, reduced once after the loop. VGPR 72 -> 3 blocks/CU
// (register cliff: do NOT add live state). exp via raw v_exp_f32 (R12 win).
__global__ __launch_bounds__(256) void attn_mfma(
    const __hip_bfloat16* __restrict__ qg,   // [B,H,N,64]
    const __hip_bfloat16* __restrict__ kg,   // [B,H,N,64]
    const __hip_bfloat16* __restrict__ vtg,  // [B,H,64,N]
    const float* __restrict__ gate_h,
    __hip_bfloat16* __restrict__ og)         // [B,N,C]
{
    __shared__ __align__(16) unsigned short Ks [3][64*64];
    __shared__ __align__(16) unsigned short Vts[3][64*64];
    const int t = threadIdx.x;
    const int l = t & 63;
    const int w = t >> 6;
    // XCD swizzle: 96 bh over 8 XCDs = 12 bh/XCD, 8 q-tiles each contiguous
    const int X  = blockIdx.x & 7;
    const int j8 = blockIdx.x >> 3;          // 0..95
    const int bh = X*12 + (j8 >> 3);
    const int n0 = (j8 & 7) * 128;
    const int h  = bh % H_;
    const int b  = bh / H_;
    const unsigned short* qp  = (const unsigned short*)qg  + ((size_t)bh*N_ + n0 + w*32)*64;
    const unsigned short* kp  = (const unsigned short*)kg  + (size_t)bh*N_*64;
    const unsigned short* vtp = (const unsigned short*)vtg + (size_t)bh*64*N_;

    // Q fragments (B-operand layout), scale*log2e folded in
    bf16x8 qf[2][2];
    #pragma unroll
    for (int mt=0;mt<2;mt++)
        #pragma unroll
        for (int dc=0;dc<2;dc++){
            u16x8 raw = *(const u16x8*)(qp + ((size_t)(mt*16 + (l&15)))*64 + dc*32 + (l>>4)*8);
            u16x8 sc;
            #pragma unroll
            for (int j=0;j<8;j++) sc[j] = f2bf(bf2f(raw[j]) * 0.1803368801111244f);
            qf[mt][dc] = __builtin_bit_cast(bf16x8, sc);
        }

    // pre-hoisted ds_read byte offsets (lane-dependent, kt-invariant)
    int qk_off[4][2], pv_off[2][4];
    #pragma unroll
    for (int t4=0;t4<4;t4++){
        const int i    = l & 15;
        const int row  = 8*(i>>2) + (i&3) + 4*(t4&1) + 32*(t4>>1);   // phys_k(t4, i)
        const int swzr = (row&3) | (((row>>3)&1)<<2);
        #pragma unroll
        for (int dc=0;dc<2;dc++)
            qk_off[t4][dc] = row*128 + ((dc*64 + (l>>4)*16) ^ (swzr<<4));
    }
    #pragma unroll
    for (int nt=0;nt<4;nt++){
        const int row  = nt*16 + (l&15);
        const int swzr = (row&3) | (((row>>3)&1)<<2);
        #pragma unroll
        for (int kc=0;kc<2;kc++)
            pv_off[kc][nt] = row*128 + ((kc*64 + (l>>4)*16) ^ (swzr<<4));
    }

    const int sr  = t >> 3;        // staging row 0..31 (and +32)
    const int sce = (t & 7) * 8;   // staging col (elements) before swizzle

    auto STAGE = [&](int buf, int kt){
        #pragma unroll
        for (int c=0;c<2;c++){
            const int r    = sr + c*32;
            const int swzr = (r&3) | (((r>>3)&1)<<2);
            const int col  = sce ^ (swzr<<3);           // inverse-swizzled global col
            gload16(kp  + ((size_t)(kt*64 + r))*64 + col, (char*)&Ks [buf][0] + (c*256 + t)*16);
            gload16(vtp + (size_t)r*N_ + kt*64 + col,     (char*)&Vts[buf][0] + (c*256 + t)*16);
        }
    };

    f32x4 o_acc[2][4];
    #pragma unroll
    for (int i=0;i<2;i++)
        #pragma unroll
        for (int jj=0;jj<4;jj++) o_acc[i][jj] = (f32x4){0.f,0.f,0.f,0.f};
    float rs_part[2] = {0.f, 0.f};   // per-lane partial denominators (k is lane-local)

    STAGE(0, 0);
    STAGE(1, 1);
    int cur = 0, stb = 2;
    for (int kt=0; kt<16; kt++){
        if (kt < 15) asm volatile("s_waitcnt vmcnt(4)" ::: "memory");  // own tile done; next in flight
        else         asm volatile("s_waitcnt vmcnt(0)" ::: "memory");
        __builtin_amdgcn_s_barrier();
        asm volatile("" ::: "memory");
        if (kt < 14){
            STAGE(stb, kt+2);
            stb = (stb+1==3) ? 0 : stb+1;
        }
        const char* ks = (const char*)&Ks[cur][0];
        const char* vs = (const char*)&Vts[cur][0];

        // QK^T (swapped): A=K (permuted rows), B=Q
        f32x4 s_acc[4][2];
        #pragma unroll
        for (int i=0;i<4;i++)
            #pragma unroll
            for (int jj=0;jj<2;jj++) s_acc[i][jj] = (f32x4){0.f,0.f,0.f,0.f};
        #pragma unroll
        for (int t4=0;t4<4;t4++)
            #pragma unroll
            for (int dc=0;dc<2;dc++){
                bf16x8 kf = *(const bf16x8*)(ks + qk_off[t4][dc]);
                #pragma unroll
                for (int mt=0;mt<2;mt++)
                    s_acc[t4][mt] = __builtin_amdgcn_mfma_f32_16x16x32_bf16(kf, qf[mt][dc], s_acc[t4][mt], 0,0,0);
            }
        // exp via raw v_exp_f32 (scale pre-folded; scores bounded) + per-lane partials
        #pragma unroll
        for (int mt=0;mt<2;mt++){
            float acc_s = 0.f;
            #pragma unroll
            for (int t4=0;t4<4;t4++){
                #pragma unroll
                for (int jj=0;jj<4;jj++){
                    float e = fast_exp2(s_acc[t4][mt][jj]);
                    s_acc[t4][mt][jj] = e;
                    acc_s += e;
                }
            }
            rs_part[mt] += acc_s;
        }
        // PV: P-fragments packed in-register (lane-local k-ownership)
        #pragma unroll
        for (int kc=0;kc<2;kc++){
            union { unsigned int u[4]; bf16x8 v; } pu[2];
            #pragma unroll
            for (int mt=0;mt<2;mt++){
                pu[mt].u[0] = cvt_pk_bf16(s_acc[2*kc  ][mt][0], s_acc[2*kc  ][mt][1]);
                pu[mt].u[1] = cvt_pk_bf16(s_acc[2*kc  ][mt][2], s_acc[2*kc  ][mt][3]);
                pu[mt].u[2] = cvt_pk_bf16(s_acc[2*kc+1][mt][0], s_acc[2*kc+1][mt][1]);
                pu[mt].u[3] = cvt_pk_bf16(s_acc[2*kc+1][mt][2], s_acc[2*kc+1][mt][3]);
            }
            #pragma unroll
            for (int nt=0;nt<4;nt++){
                bf16x8 vf = *(const bf16x8*)(vs + pv_off[kc][nt]);
                #pragma unroll
                for (int mt=0;mt<2;mt++)
                    o_acc[mt][nt] = __builtin_amdgcn_mfma_f32_16x16x32_bf16(pu[mt].v, vf, o_acc[mt][nt], 0,0,0);
            }
        }
        cur = (cur+1==3) ? 0 : cur+1;
    }
    // final denominator: reduce across the 4 lane-groups, then broadcast to output layout
    float rowsum[2];
    #pragma unroll
    for (int mt=0;mt<2;mt++){
        float rs = rs_part[mt];
        rs += __shfl_xor(rs, 16);
        rs += __shfl_xor(rs, 32);
        rowsum[mt] = rs;           // full sum for q = mt*16 + (l&15), uniform across groups
    }
    const float gh = gate_h[h];
    float inv[2][4];
    #pragma unroll
    for (int mt=0;mt<2;mt++)
        #pragma unroll
        for (int r=0;r<4;r++)
            inv[mt][r] = gh / __shfl(rowsum[mt], (l>>4)*4 + r, 16);
    // epilogue: normalize, gate, write O[b][n][h*64+d]
    unsigned short* op = (unsigned short*)og + ((size_t)b*N_ + n0 + w*32)*C_ + h*64;
    #pragma unroll
    for (int mt=0;mt<2;mt++){
        #pragma unroll
        for (int r=0;r<4;r++){
            const int n = mt*16 + (l>>4)*4 + r;
            #pragma unroll
            for (int nt=0;nt<4;nt++)
                op[(size_t)n*C_ + nt*16 + (l&15)] = f2bf(o_acc[mt][nt][r]*inv[mt][r]);
        }
    }
}

// ---------------- launch ----------------
extern "C" void kernel_launch(void* const* d_in, const int* in_sizes, int n_in,
                              void* d_out, int out_size, void* d_ws, size_t ws_size,
                              hipStream_t stream)
{
    const float* x     = (const float*)d_in[0];
    const float* ln1g  = (const float*)d_in[1];
    const float* ln1b  = (const float*)d_in[2];
    const float* qkvw  = (const float*)d_in[3];
    const float* projw = (const float*)d_in[4];
    const float* projb = (const float*)d_in[5];
    const float* gateh = (const float*)d_in[6];
    const float* ln2g  = (const float*)d_in[7];
    const float* ln2b  = (const float*)d_in[8];
    const float* fc1w  = (const float*)d_in[9];
    const float* fc1b  = (const float*)d_in[10];
    const float* fc2w  = (const float*)d_in[11];
    const float* fc2b  = (const float*)d_in[12];
    const float* gatem = (const float*)d_in[13];
    float* out = (float*)d_out;

    char* ws = (char*)d_ws;
    __hip_bfloat16* h_buf = (__hip_bfloat16*)(ws + 0);          // 12.58MB  (h / h2)
    __hip_bfloat16* qkv   = (__hip_bfloat16*)(ws + 12582912);   // 37.75MB  (q,k,v^T)
    __hip_bfloat16* q_buf = qkv;
    __hip_bfloat16* k_buf = qkv + 6291456;
    __hip_bfloat16* vt_buf= qkv + 2*6291456;
    __hip_bfloat16* o_buf = (__hip_bfloat16*)(ws + 50331648);   // 12.58MB
    __hip_bfloat16* m_buf = (__hip_bfloat16*)(ws + 12582912);   // 50.33MB (reuses dead qkv+o)
    __hip_bfloat16* x1b   = (__hip_bfloat16*)(ws + 62914560);   // 12.58MB (bf16 residual)
    __hip_bfloat16* wqkv  = (__hip_bfloat16*)(ws + 88080384);
    __hip_bfloat16* wproj = (__hip_bfloat16*)(ws + 88965120);
    __hip_bfloat16* wfc1  = (__hip_bfloat16*)(ws + 89260032);
    __hip_bfloat16* wfc2  = (__hip_bfloat16*)(ws + 90439680);

    // LN1 + all weight converts, one launch (independent memory-bound tasks)
    ln1_cvt_kernel<<<5120, 256, 0, stream>>>(x, ln1g, ln1b, h_buf,
                                             qkvw, wqkv, 1152*384,
                                             projw, wproj, 384*384,
                                             fc1w, wfc1, 1536*384,
                                             fc2w, wfc2, 384*1536);

    // R8: all K=384 GEMMs -> wres4 (deep lead, RT=1); FC2 (K=1536) stays gemm_bt
    gemm_wres4<EPI_QKV,1152><<<2304, 256, 0, stream>>>(h_buf, wqkv, nullptr, nullptr, nullptr, qkv);
    attn_mfma<<<768, 256, 0, stream>>>(q_buf, k_buf, vt_buf, gateh, o_buf);
    gemm_wres4<EPI_PROJ,384><<<768, 256, 0, stream>>>(o_buf, wproj, projb, x, nullptr, x1b);
    ln_kernel<__hip_bfloat16><<<4096, 256, 0, stream>>>(x1b, ln2g, ln2b, h_buf);
    gemm_wres4<EPI_FC1,1536><<<3072, 256, 0, stream>>>(h_buf, wfc1, fc1b, nullptr, gatem, m_buf);
    gemm_bt<EPI_FC2,64,128,3,1,256><<<768, 256, 0, stream>>>(m_buf, wfc2, R_, 384, 1536,
                                                             fc2b, nullptr, x1b, nullptr, out, nullptr);
}

// Round 9
// 173.733 us; speedup vs baseline: 1.1139x; 1.0039x over previous
//
#include <hip/hip_runtime.h>
#include <hip/hip_bf16.h>
#include <cstdint>
#include <cstddef>

#define B_   16
#define N_   1024
#define C_   384
#define H_   6
#define DFF_ 1536
#define R_   16384   // B_*N_

typedef __attribute__((ext_vector_type(8))) __bf16 bf16x8;
typedef __attribute__((ext_vector_type(4))) float  f32x4;
typedef __attribute__((ext_vector_type(8))) unsigned short u16x8;
typedef __attribute__((ext_vector_type(4))) unsigned short u16x4;

__device__ __forceinline__ float bf2f(unsigned short u){
    unsigned int x = ((unsigned int)u) << 16;
    return __builtin_bit_cast(float, x);
}
__device__ __forceinline__ unsigned short f2bf(float f){
    return __builtin_bit_cast(unsigned short, __float2bfloat16(f));
}
__device__ __forceinline__ unsigned int cvt_pk_bf16(float a, float b){
    unsigned int r;
    asm("v_cvt_pk_bf16_f32 %0, %1, %2" : "=v"(r) : "v"(a), "v"(b));
    return r;   // lo = bf16(a), hi = bf16(b)
}
// raw v_exp_f32 (2^x). Args provably in [-45,0] -> no OCML range/denorm fixup needed.
__device__ __forceinline__ float fast_exp2(float x){
    float r;
    asm("v_exp_f32 %0, %1" : "=v"(r) : "v"(x));
    return r;
}
__device__ __forceinline__ void gload16(const void* g, void* l){
    __builtin_amdgcn_global_load_lds(
        (const __attribute__((address_space(1))) unsigned int*)g,
        (__attribute__((address_space(3))) unsigned int*)l, 16, 0, 0);
}
// exact-GELU via Abramowitz-Stegun 7.1.25 erf approx (|err| <= 2.5e-5)
__device__ __forceinline__ float gelu_f(float u){
    float z  = fabsf(u) * 0.70710678118654752f;
    float t  = __builtin_amdgcn_rcpf(1.0f + 0.47047f*z);
    float e  = __expf(-z*z);
    float p  = t*(0.3480242f + t*(-0.0958798f + t*0.7478556f));
    float er = 1.0f - p*e;                       // erf(z), z>=0
    return 0.5f*u*(1.0f + copysignf(er, u));
}
__device__ __forceinline__ float ldv(const float* p, size_t i){ return p[i]; }
__device__ __forceinline__ float ldv(const __hip_bfloat16* p, size_t i){ return __bfloat162float(p[i]); }

// ---------------- LN1 + all-weight fp32->bf16 convert, one launch ----------------
__global__ __launch_bounds__(256) void ln1_cvt_kernel(
    const float* __restrict__ x, const float* __restrict__ g,
    const float* __restrict__ b, __hip_bfloat16* __restrict__ out,
    const float* __restrict__ i0, __hip_bfloat16* __restrict__ o0, int n0,
    const float* __restrict__ i1, __hip_bfloat16* __restrict__ o1, int n1,
    const float* __restrict__ i2, __hip_bfloat16* __restrict__ o2, int n2,
    const float* __restrict__ i3, __hip_bfloat16* __restrict__ o3, int n3)
{
    if (blockIdx.x < 4096){
        const int lane = threadIdx.x & 63;
        const int wave = threadIdx.x >> 6;
        const int row  = blockIdx.x*4 + wave;
        const float* xr = x + (size_t)row*C_;
        float v[6];
        float s = 0.f;
        #pragma unroll
        for (int i=0;i<6;i++){ v[i] = xr[lane + i*64]; s += v[i]; }
        #pragma unroll
        for (int m=1;m<64;m<<=1) s += __shfl_xor(s, m);
        const float mean = s * (1.0f/C_);
        float sq = 0.f;
        #pragma unroll
        for (int i=0;i<6;i++){ float d = v[i]-mean; sq += d*d; }
        #pragma unroll
        for (int m=1;m<64;m<<=1) sq += __shfl_xor(sq, m);
        const float rstd = rsqrtf(sq*(1.0f/C_) + 1e-5f);
        #pragma unroll
        for (int i=0;i<6;i++){
            int c = lane + i*64;
            out[(size_t)row*C_ + c] = __float2bfloat16((v[i]-mean)*rstd*g[c] + b[c]);
        }
    } else {
        const int total = n0+n1+n2+n3;
        for (int i = (blockIdx.x-4096)*blockDim.x + threadIdx.x; i < total; i += 1024*blockDim.x){
            int k = i;
            if (k < n0){ o0[k] = __float2bfloat16(i0[k]); continue; }
            k -= n0;
            if (k < n1){ o1[k] = __float2bfloat16(i1[k]); continue; }
            k -= n1;
            if (k < n2){ o2[k] = __float2bfloat16(i2[k]); continue; }
            k -= n2;
            o3[k] = __float2bfloat16(i3[k]);
        }
    }
}

// ---------------- LayerNorm: (fp32|bf16) in -> bf16 out ----------------
template<typename T>
__global__ __launch_bounds__(256) void ln_kernel(
    const T* __restrict__ x, const float* __restrict__ g,
    const float* __restrict__ b, __hip_bfloat16* __restrict__ out)
{
    const int lane = threadIdx.x & 63;
    const int wave = threadIdx.x >> 6;
    const int row  = blockIdx.x*4 + wave;
    const T* xr = x + (size_t)row*C_;
    float v[6];
    float s = 0.f;
    #pragma unroll
    for (int i=0;i<6;i++){ v[i] = ldv(xr, lane + i*64); s += v[i]; }
    #pragma unroll
    for (int m=1;m<64;m<<=1) s += __shfl_xor(s, m);
    const float mean = s * (1.0f/C_);
    float sq = 0.f;
    #pragma unroll
    for (int i=0;i<6;i++){ float d = v[i]-mean; sq += d*d; }
    #pragma unroll
    for (int m=1;m<64;m<<=1) sq += __shfl_xor(sq, m);
    const float rstd = rsqrtf(sq*(1.0f/C_) + 1e-5f);
    #pragma unroll
    for (int i=0;i<6;i++){
        int c = lane + i*64;
        out[(size_t)row*C_ + c] = __float2bfloat16((v[i]-mean)*rstd*g[c] + b[c]);
    }
}

// ---------------- bf16 MFMA GEMM, BK=32, NBUF-buffer single-barrier pipeline ----------------
// (Retained for FC2 only: K=1536 -> 48 steps, prologue amortized, B panel too big for wres.)
#define BK2 32
enum { EPI_QKV=0, EPI_PROJ=1, EPI_FC1=2, EPI_FC2=3 };

template<int EPI, int BMt, int BNt, int NBUF, int MW, int NTH>
__global__ __launch_bounds__(NTH, MW) void gemm_bt(
    const __hip_bfloat16* __restrict__ A,
    const __hip_bfloat16* __restrict__ W,
    const int M, const int N, const int K,
    const float* __restrict__ bias,
    const float* __restrict__ resid,
    const __hip_bfloat16* __restrict__ residb,
    const float* __restrict__ gate,
    float* __restrict__ outf,
    __hip_bfloat16* __restrict__ outb)
{
    constexpr int NWAVE = NTH/64;
    constexpr int NWC   = (BNt >= 128) ? 2 : 1;   // wave-cols
    constexpr int NWR   = NWAVE/NWC;              // wave-rows
    constexpr int WRS   = BMt/NWR;                // output rows per wave
    constexpr int MI    = WRS/16;                 // acc row-frags per wave
    constexpr int APASS = (BMt*BK2*2)/(NTH*16);   // A staging passes
    constexpr int BPASS = (BNt*BK2*2)/(NTH*16);   // B staging passes
    constexpr int LPT   = APASS + BPASS;          // gload_lds per STAGE per thread
    constexpr int RPP   = NTH/4;                  // staging rows per pass
    __shared__ __align__(16) unsigned short As[NBUF][BMt*BK2];
    __shared__ __align__(16) unsigned short Bs[NBUF][BNt*BK2];
    const int t = threadIdx.x;
    const int l = t & 63;
    const int w = t >> 6;
    const int wr = (NWC==2) ? (w >> 1) : w;
    const int wc = (NWC==2) ? (w & 1)  : 0;
    const int nb = N / BNt;
    const int rbX = (M/BMt) >> 3;
    const int X  = blockIdx.x & 7;
    const int j8 = blockIdx.x >> 3;
    const int rb = X*rbX + j8 / nb;
    const int cb = j8 % nb;
    const int srow2 = t >> 2;                          // staging row within pass
    const int sgcol = (((t&3) - ((t>>3)&3)) & 3) * 8;  // chunk-rotation global col
    f32x4 acc[MI][4];
    #pragma unroll
    for (int i=0;i<MI;i++)
        #pragma unroll
        for (int jj=0;jj<4;jj++) acc[i][jj] = (f32x4){0.f,0.f,0.f,0.f};

    const size_t arow0 = (size_t)rb*BMt + srow2;
    const size_t brow0 = (size_t)cb*BNt + srow2;

    auto STAGE = [&](int buf, int k0){
        #pragma unroll
        for (int c=0;c<APASS;c++)
            gload16(A + (arow0 + c*RPP)*K + k0 + sgcol, (char*)&As[buf][0] + c*(NTH*16) + t*16);
        #pragma unroll
        for (int c=0;c<BPASS;c++)
            gload16(W + (brow0 + c*RPP)*K + k0 + sgcol, (char*)&Bs[buf][0] + c*(NTH*16) + t*16);
    };

    auto COMPUTE = [&](int buf){
        const char* as = (const char*)&As[buf][0];
        const char* bs = (const char*)&Bs[buf][0];
        bf16x8 af[MI], bw[4];
        #pragma unroll
        for (int i=0;i<MI;i++){
            const int r = wr*WRS + i*16 + (l&15);
            const int sl = ((l>>4) + ((r>>1)&3)) & 3;
            af[i] = *(const bf16x8*)(as + r*64 + sl*16);
        }
        #pragma unroll
        for (int i=0;i<4;i++){
            const int r = wc*64 + i*16 + (l&15);
            const int sl = ((l>>4) + ((r>>1)&3)) & 3;
            bw[i] = *(const bf16x8*)(bs + r*64 + sl*16);
        }
        #pragma unroll
        for (int mi=0;mi<MI;mi++)
            #pragma unroll
            for (int ni=0;ni<4;ni++)
                acc[mi][ni] = __builtin_amdgcn_mfma_f32_16x16x32_bf16(af[mi], bw[ni], acc[mi][ni], 0,0,0);
    };

    const int nst = K/BK2;
    if constexpr (NBUF==2){
        STAGE(0, 0);
        for (int s=0; s<nst; ++s){
            asm volatile("s_waitcnt vmcnt(0)" ::: "memory");   // only own tile-s loads in flight
            __builtin_amdgcn_s_barrier();
            asm volatile("" ::: "memory");
            if (s+1 < nst) STAGE((s+1)&1, (s+1)*BK2);
            COMPUTE(s&1);
        }
    } else {   // NBUF==3
        STAGE(0, 0);
        STAGE(1, BK2);
        int cur = 0, stb = 2;
        for (int s=0; s<nst; ++s){
            if (s < nst-1){
                if constexpr (LPT==4) asm volatile("s_waitcnt vmcnt(4)" ::: "memory");
                else                  asm volatile("s_waitcnt vmcnt(3)" ::: "memory");
            } else {
                asm volatile("s_waitcnt vmcnt(0)" ::: "memory");
            }
            __builtin_amdgcn_s_barrier();
            asm volatile("" ::: "memory");
            if (s+2 < nst){
                STAGE(stb, (s+2)*BK2);
                stb = (stb+1==3) ? 0 : stb+1;
            }
            COMPUTE(cur);
            cur = (cur+1==3) ? 0 : cur+1;
        }
    }
    // epilogue: C/D layout: col = lane&15, row = (lane>>4)*4 + reg
    const int rowBase = rb*BMt + wr*WRS;
    const int colBase = cb*BNt + wc*64;
    #pragma unroll
    for (int ni=0; ni<4; ni++){
        const int col = colBase + ni*16 + (l&15);
        #pragma unroll
        for (int mi=0; mi<MI; mi++){
            #pragma unroll
            for (int jj=0;jj<4;jj++){
                const int row = rowBase + mi*16 + (l>>4)*4 + jj;
                const float vx = acc[mi][ni][jj];
                size_t idx = (size_t)row*N + col;
                if constexpr (EPI==EPI_PROJ){
                    outb[idx] = __float2bfloat16(resid[idx] + vx + bias[col]);   // x1 in bf16
                } else if constexpr (EPI==EPI_FC2){
                    outf[idx] = bf2f(*((const unsigned short*)residb + idx)) + vx + bias[col];
                } else { // EPI_FC1: GELU (A&S erf) * gate
                    outb[idx] = __float2bfloat16(gelu_f(vx + bias[col]) * gate[col]);
                }
            }
        }
    }
}

// ---------------- R9 consolidation: per-op best-measured configs ----------------
// Per-op ledger (us, per-dispatch where visible):
//   FC1: 72.9(2bar) 68.6(NBUF3) 59.2(BNt64) 59.5(NBUF4) 55.4(wres) 61.8(wres RT2)
//        63.2(areg) ~52(wres4 RT1)  -> BEST = wres4 RT1
//   QKV/proj: best TOTAL (171.0) came with wres RT2 (R6); moving them to wres4 RT1
//        (R8) cost ~+12us while FC1 gained 9 -> BEST = wres RT2
// RT2 helps QKV/proj (halved B-panel prologues dominate) but hurts FC1 (tile-0
// epilogue stores poison tile-1's counted vmcnt). Per-shape configs, per lesson R3.

// gemm_wres: RT=2 (R6 exact) -- B panel resident, 4 A-bands, G=24 cross-tile pipeline
template<int EPI, int NCOLS>   // NCOLS: 1152 (QKV) / 384 (proj)
__global__ __launch_bounds__(256, 2) void gemm_wres(
    const __hip_bfloat16* __restrict__ A,    // [16384, 384]
    const __hip_bfloat16* __restrict__ Wt,   // [NCOLS, 384]
    const float* __restrict__ bias,
    const float* __restrict__ resid,
    const float* __restrict__ gate,
    __hip_bfloat16* __restrict__ outb)
{
    constexpr int NB = NCOLS/64;             // col-blocks
    constexpr int G  = 24;                   // RT=2 tiles x 12 K-steps
    __shared__ __align__(16) unsigned short As[4][128*32];   // 32KB: 4 bands, wave-private 32rx32k
    __shared__ __align__(16) unsigned short Bs[64*384];      // 48KB: whole-K weight panel
    const int t = threadIdx.x;
    const int l = t & 63;
    const int w = t >> 6;
    const int X  = blockIdx.x & 7;
    const int j8 = blockIdx.x >> 3;
    const int rb = X*8 + j8 / NB;            // row-group 0..63 (256 rows each)
    const int cb = j8 % NB;

    // ---- B panel: whole K staged once, 12 gload16/thread, pre-swizzled source ----
    #pragma unroll
    for (int j=0;j<12;j++){
        const int L     = (w*12 + j)*1024 + l*16;       // linear LDS byte (gload_lds HW rule)
        const int row   = L / 768;                      // B row 0..63
        const int cbyte = L - row*768;
        const int scol  = (cbyte ^ ((row&7)<<4)) >> 1;  // inverse-swizzled source col (elems)
        gload16(Wt + (size_t)(cb*64 + row)*384 + scol, (char*)&Bs[0] + L);
    }
    // ---- A bands: wave-private, 2 gload16 per band (32 rows x 32 K) ----
    const int sgcol = (((l&3) - ((l>>3)&3)) & 3) * 8;
    const size_t arow0 = (size_t)rb*256 + w*32 + (l>>2);
    auto STAGEA = [&](int g){
        const int rt = g/12, s = g - rt*12;
        #pragma unroll
        for (int c=0;c<2;c++)
            gload16(A + (arow0 + rt*128 + c*16)*384 + s*32 + sgcol,
                    (char*)&As[g&3][0] + w*2048 + c*1024 + l*16);
    };
    STAGEA(0); STAGEA(1); STAGEA(2);
    asm volatile("s_waitcnt vmcnt(6)" ::: "memory");    // 12 B loads drained; 3 bands in flight
    __builtin_amdgcn_s_barrier();                        // the ONLY barrier

    #pragma unroll
    for (int rt=0; rt<2; ++rt){
        f32x4 acc[2][4];
        #pragma unroll
        for (int i=0;i<2;i++)
            #pragma unroll
            for (int jj=0;jj<4;jj++) acc[i][jj] = (f32x4){0.f,0.f,0.f,0.f};

        #pragma unroll
        for (int s=0; s<12; ++s){
            const int g = rt*12 + s;
            if (g <= G-3)      asm volatile("s_waitcnt vmcnt(4)" ::: "memory");  // band g ready; 2 newer in flight
            else if (g == G-2) asm volatile("s_waitcnt vmcnt(2)" ::: "memory");
            else               asm volatile("s_waitcnt vmcnt(0)" ::: "memory");
            const char* as = (const char*)&As[g&3][0] + w*2048;
            bf16x8 af[2], bw[4];
            #pragma unroll
            for (int i=0;i<2;i++){
                const int r  = i*16 + (l&15);
                const int sl = ((l>>4) + ((r>>1)&3)) & 3;
                af[i] = *(const bf16x8*)(as + r*64 + sl*16);
            }
            #pragma unroll
            for (int i=0;i<4;i++){
                const int r = i*16 + (l&15);                  // B row (output col) 0..63
                bw[i] = *(const bf16x8*)((const char*)&Bs[0] + r*768
                             + ((s*64 + (l>>4)*16) ^ ((r&7)<<4)));
            }
            #pragma unroll
            for (int mi=0;mi<2;mi++)
                #pragma unroll
                for (int ni=0;ni<4;ni++)
                    acc[mi][ni] = __builtin_amdgcn_mfma_f32_16x16x32_bf16(af[mi], bw[ni], acc[mi][ni], 0,0,0);
            asm volatile("s_waitcnt lgkmcnt(0)" ::: "memory");  // own ds_reads retired before band overwrite
            if (g+3 < G) STAGEA(g+3);
        }
        // ---- per-tile epilogue ----
        const int rowBase = rb*256 + rt*128 + w*32;
        if constexpr (EPI==EPI_QKV){
            // scatter: Q,K -> [p][B][H][N][64]; V (p==2) -> [B][H][64][N] (transposed)
            unsigned short* ob = (unsigned short*)outb;
            #pragma unroll
            for (int ni=0; ni<4; ni++){
                const int col = cb*64 + ni*16 + (l&15);
                const int p = col/384, rem = col - p*384;
                const int hh = rem>>6, d = rem&63;
                #pragma unroll
                for (int mi=0; mi<2; mi++){
                    const int row0 = rowBase + mi*16 + (l>>4)*4;
                    const int bb = row0>>10, n = row0&1023;
                    if (p==2){
                        u16x4 pk;
                        #pragma unroll
                        for (int jj=0;jj<4;jj++) pk[jj] = f2bf(acc[mi][ni][jj]);
                        *(u16x4*)(ob + (size_t)2*6291456 + ((size_t)(bb*H_+hh)*64 + d)*1024 + n) = pk;
                    } else {
                        #pragma unroll
                        for (int jj=0;jj<4;jj++)
                            ob[(((size_t)((p*16+bb)*6+hh))<<16) + ((size_t)(n+jj)<<6) + d] = f2bf(acc[mi][ni][jj]);
                    }
                }
            }
        } else {
            #pragma unroll
            for (int ni=0; ni<4; ni++){
                const int col = cb*64 + ni*16 + (l&15);
                #pragma unroll
                for (int mi=0; mi<2; mi++){
                    #pragma unroll
                    for (int jj=0;jj<4;jj++){
                        const int row = rowBase + mi*16 + (l>>4)*4 + jj;
                        const size_t idx = (size_t)row*NCOLS + col;
                        if constexpr (EPI==EPI_PROJ){
                            outb[idx] = __float2bfloat16(resid[idx] + acc[mi][ni][jj] + bias[col]);
                        } else { // EPI_FC1 (unused here)
                            outb[idx] = __float2bfloat16(gelu_f(acc[mi][ni][jj] + bias[col]) * gate[col]);
                        }
                    }
                }
            }
        }
    }
}

// gemm_wres4: RT=1 (R8 exact) -- B panel resident, 4 A-bands deep lead, epilogue after loop
template<int EPI, int NCOLS>   // NCOLS: 1536 (FC1)
__global__ __launch_bounds__(256, 2) void gemm_wres4(
    const __hip_bfloat16* __restrict__ A,    // [16384, 384]
    const __hip_bfloat16* __restrict__ Wt,   // [NCOLS, 384]
    const float* __restrict__ bias,
    const float* __restrict__ resid,
    const float* __restrict__ gate,
    __hip_bfloat16* __restrict__ outb)
{
    constexpr int NB = NCOLS/64;             // col-blocks
    __shared__ __align__(16) unsigned short As[4][128*32];   // 32KB: 4 bands, wave-private 32rx32k
    __shared__ __align__(16) unsigned short Bs[64*384];      // 48KB: whole-K weight panel
    const int t = threadIdx.x;
    const int l = t & 63;
    const int w = t >> 6;
    const int X  = blockIdx.x & 7;
    const int j8 = blockIdx.x >> 3;
    const int rb = X*16 + j8 / NB;           // row-block 0..127 (128 rows each)
    const int cb = j8 % NB;

    // ---- B panel: whole K staged once, 12 gload16/thread, pre-swizzled source ----
    #pragma unroll
    for (int j=0;j<12;j++){
        const int L     = (w*12 + j)*1024 + l*16;       // linear LDS byte (gload_lds HW rule)
        const int row   = L / 768;                      // B row 0..63
        const int cbyte = L - row*768;
        const int scol  = (cbyte ^ ((row&7)<<4)) >> 1;  // inverse-swizzled source col (elems)
        gload16(Wt + (size_t)(cb*64 + row)*384 + scol, (char*)&Bs[0] + L);
    }
    // ---- A bands: wave-private, 2 gload16 per band (32 rows x 32 K) ----
    const int sgcol = (((l&3) - ((l>>3)&3)) & 3) * 8;
    const size_t arow0 = (size_t)rb*128 + w*32 + (l>>2);
    auto STAGEA = [&](int g){
        #pragma unroll
        for (int c=0;c<2;c++)
            gload16(A + (arow0 + c*16)*384 + g*32 + sgcol,
                    (char*)&As[g&3][0] + w*2048 + c*1024 + l*16);
    };
    STAGEA(0); STAGEA(1); STAGEA(2);
    asm volatile("s_waitcnt vmcnt(6)" ::: "memory");    // 12 B loads drained; 3 bands in flight
    __builtin_amdgcn_s_barrier();                        // the ONLY barrier

    f32x4 acc[2][4];
    #pragma unroll
    for (int i=0;i<2;i++)
        #pragma unroll
        for (int jj=0;jj<4;jj++) acc[i][jj] = (f32x4){0.f,0.f,0.f,0.f};

    #pragma unroll
    for (int s=0; s<12; ++s){
        if (s < 10)      asm volatile("s_waitcnt vmcnt(4)" ::: "memory");  // band s ready; 2 newer in flight
        else if (s == 10) asm volatile("s_waitcnt vmcnt(2)" ::: "memory");
        else              asm volatile("s_waitcnt vmcnt(0)" ::: "memory");
        const char* as = (const char*)&As[s&3][0] + w*2048;
        bf16x8 af[2], bw[4];
        #pragma unroll
        for (int i=0;i<2;i++){
            const int r  = i*16 + (l&15);                 // local band row 0..31
            const int sl = ((l>>4) + ((r>>1)&3)) & 3;
            af[i] = *(const bf16x8*)(as + r*64 + sl*16);
        }
        #pragma unroll
        for (int i=0;i<4;i++){
            const int r = i*16 + (l&15);                  // B row (output col) 0..63
            bw[i] = *(const bf16x8*)((const char*)&Bs[0] + r*768
                         + ((s*64 + (l>>4)*16) ^ ((r&7)<<4)));
        }
        #pragma unroll
        for (int mi=0;mi<2;mi++)
            #pragma unroll
            for (int ni=0;ni<4;ni++)
                acc[mi][ni] = __builtin_amdgcn_mfma_f32_16x16x32_bf16(af[mi], bw[ni], acc[mi][ni], 0,0,0);
        asm volatile("s_waitcnt lgkmcnt(0)" ::: "memory");  // own ds_reads retired before band overwrite
        if (s+3 < 12) STAGEA(s+3);                          // writes band (s-1)&3, reads retired at s-1
    }

    // ---- epilogue (after loop: stores cannot poison counted waits) ----
    const int rowBase = rb*128 + w*32;
    #pragma unroll
    for (int ni=0; ni<4; ni++){
        const int col = cb*64 + ni*16 + (l&15);
        #pragma unroll
        for (int mi=0; mi<2; mi++){
            #pragma unroll
            for (int jj=0;jj<4;jj++){
                const int row = rowBase + mi*16 + (l>>4)*4 + jj;
                const size_t idx = (size_t)row*NCOLS + col;
                if constexpr (EPI==EPI_PROJ){
                    outb[idx] = __float2bfloat16(resid[idx] + acc[mi][ni][jj] + bias[col]);
                } else { // EPI_FC1
                    outb[idx] = __float2bfloat16(gelu_f(acc[mi][ni][jj] + bias[col]) * gate[col]);
                }
            }
        }
    }
}

// ---------------- MFMA flash attention, 3-buffer single-barrier pipeline (R12-best) ----------------
// QBLK=128 (grid 768): 4 waves, wave w owns 32 q-rows. In-register P via swapped QK^T
// + phys_k permutation (lane-local k-ownership -> P packed via v_cvt_pk_bf16_f32).
// Per-lane rs_part denominators, reduced once after the loop. VGPR 72 -> 3 blocks/CU
// (register cliff: do NOT add live state). exp via raw v_exp_f32 (R12 win).
__global__ __launch_bounds__(256) void attn_mfma(
    const __hip_bfloat16* __restrict__ qg,   // [B,H,N,64]
    const __hip_bfloat16* __restrict__ kg,   // [B,H,N,64]
    const __hip_bfloat16* __restrict__ vtg,  // [B,H,64,N]
    const float* __restrict__ gate_h,
    __hip_bfloat16* __restrict__ og)         // [B,N,C]
{
    __shared__ __align__(16) unsigned short Ks [3][64*64];
    __shared__ __align__(16) unsigned short Vts[3][64*64];
    const int t = threadIdx.x;
    const int l = t & 63;
    const int w = t >> 6;
    // XCD swizzle: 96 bh over 8 XCDs = 12 bh/XCD, 8 q-tiles each contiguous
    const int X  = blockIdx.x & 7;
    const int j8 = blockIdx.x >> 3;          // 0..95
    const int bh = X*12 + (j8 >> 3);
    const int n0 = (j8 & 7) * 128;
    const int h  = bh % H_;
    const int b  = bh / H_;
    const unsigned short* qp  = (const unsigned short*)qg  + ((size_t)bh*N_ + n0 + w*32)*64;
    const unsigned short* kp  = (const unsigned short*)kg  + (size_t)bh*N_*64;
    const unsigned short* vtp = (const unsigned short*)vtg + (size_t)bh*64*N_;

    // Q fragments (B-operand layout), scale*log2e folded in
    bf16x8 qf[2][2];
    #pragma unroll
    for (int mt=0;mt<2;mt++)
        #pragma unroll
        for (int dc=0;dc<2;dc++){
            u16x8 raw = *(const u16x8*)(qp + ((size_t)(mt*16 + (l&15)))*64 + dc*32 + (l>>4)*8);
            u16x8 sc;
            #pragma unroll
            for (int j=0;j<8;j++) sc[j] = f2bf(bf2f(raw[j]) * 0.1803368801111244f);
            qf[mt][dc] = __builtin_bit_cast(bf16x8, sc);
        }

    // pre-hoisted ds_read byte offsets (lane-dependent, kt-invariant)
    int qk_off[4][2], pv_off[2][4];
    #pragma unroll
    for (int t4=0;t4<4;t4++){
        const int i    = l & 15;
        const int row  = 8*(i>>2) + (i&3) + 4*(t4&1) + 32*(t4>>1);   // phys_k(t4, i)
        const int swzr = (row&3) | (((row>>3)&1)<<2);
        #pragma unroll
        for (int dc=0;dc<2;dc++)
            qk_off[t4][dc] = row*128 + ((dc*64 + (l>>4)*16) ^ (swzr<<4));
    }
    #pragma unroll
    for (int nt=0;nt<4;nt++){
        const int row  = nt*16 + (l&15);
        const int swzr = (row&3) | (((row>>3)&1)<<2);
        #pragma unroll
        for (int kc=0;kc<2;kc++)
            pv_off[kc][nt] = row*128 + ((kc*64 + (l>>4)*16) ^ (swzr<<4));
    }

    const int sr  = t >> 3;        // staging row 0..31 (and +32)
    const int sce = (t & 7) * 8;   // staging col (elements) before swizzle

    auto STAGE = [&](int buf, int kt){
        #pragma unroll
        for (int c=0;c<2;c++){
            const int r    = sr + c*32;
            const int swzr = (r&3) | (((r>>3)&1)<<2);
            const int col  = sce ^ (swzr<<3);           // inverse-swizzled global col
            gload16(kp  + ((size_t)(kt*64 + r))*64 + col, (char*)&Ks [buf][0] + (c*256 + t)*16);
            gload16(vtp + (size_t)r*N_ + kt*64 + col,     (char*)&Vts[buf][0] + (c*256 + t)*16);
        }
    };

    f32x4 o_acc[2][4];
    #pragma unroll
    for (int i=0;i<2;i++)
        #pragma unroll
        for (int jj=0;jj<4;jj++) o_acc[i][jj] = (f32x4){0.f,0.f,0.f,0.f};
    float rs_part[2] = {0.f, 0.f};   // per-lane partial denominators (k is lane-local)

    STAGE(0, 0);
    STAGE(1, 1);
    int cur = 0, stb = 2;
    for (int kt=0; kt<16; kt++){
        if (kt < 15) asm volatile("s_waitcnt vmcnt(4)" ::: "memory");  // own tile done; next in flight
        else         asm volatile("s_waitcnt vmcnt(0)" ::: "memory");
        __builtin_amdgcn_s_barrier();
        asm volatile("" ::: "memory");
        if (kt < 14){
            STAGE(stb, kt+2);
            stb = (stb+1==3) ? 0 : stb+1;
        }
        const char* ks = (const char*)&Ks[cur][0];
        const char* vs = (const char*)&Vts[cur][0];

        // QK^T (swapped): A=K (permuted rows), B=Q
        f32x4 s_acc[4][2];
        #pragma unroll
        for (int i=0;i<4;i++)
            #pragma unroll
            for (int jj=0;jj<2;jj++) s_acc[i][jj] = (f32x4){0.f,0.f,0.f,0.f};
        #pragma unroll
        for (int t4=0;t4<4;t4++)
            #pragma unroll
            for (int dc=0;dc<2;dc++){
                bf16x8 kf = *(const bf16x8*)(ks + qk_off[t4][dc]);
                #pragma unroll
                for (int mt=0;mt<2;mt++)
                    s_acc[t4][mt] = __builtin_amdgcn_mfma_f32_16x16x32_bf16(kf, qf[mt][dc], s_acc[t4][mt], 0,0,0);
            }
        // exp via raw v_exp_f32 (scale pre-folded; scores bounded) + per-lane partials
        #pragma unroll
        for (int mt=0;mt<2;mt++){
            float acc_s = 0.f;
            #pragma unroll
            for (int t4=0;t4<4;t4++){
                #pragma unroll
                for (int jj=0;jj<4;jj++){
                    float e = fast_exp2(s_acc[t4][mt][jj]);
                    s_acc[t4][mt][jj] = e;
                    acc_s += e;
                }
            }
            rs_part[mt] += acc_s;
        }
        // PV: P-fragments packed in-register (lane-local k-ownership)
        #pragma unroll
        for (int kc=0;kc<2;kc++){
            union { unsigned int u[4]; bf16x8 v; } pu[2];
            #pragma unroll
            for (int mt=0;mt<2;mt++){
                pu[mt].u[0] = cvt_pk_bf16(s_acc[2*kc  ][mt][0], s_acc[2*kc  ][mt][1]);
                pu[mt].u[1] = cvt_pk_bf16(s_acc[2*kc  ][mt][2], s_acc[2*kc  ][mt][3]);
                pu[mt].u[2] = cvt_pk_bf16(s_acc[2*kc+1][mt][0], s_acc[2*kc+1][mt][1]);
                pu[mt].u[3] = cvt_pk_bf16(s_acc[2*kc+1][mt][2], s_acc[2*kc+1][mt][3]);
            }
            #pragma unroll
            for (int nt=0;nt<4;nt++){
                bf16x8 vf = *(const bf16x8*)(vs + pv_off[kc][nt]);
                #pragma unroll
                for (int mt=0;mt<2;mt++)
                    o_acc[mt][nt] = __builtin_amdgcn_mfma_f32_16x16x32_bf16(pu[mt].v, vf, o_acc[mt][nt], 0,0,0);
            }
        }
        cur = (cur+1==3) ? 0 : cur+1;
    }
    // final denominator: reduce across the 4 lane-groups, then broadcast to output layout
    float rowsum[2];
    #pragma unroll
    for (int mt=0;mt<2;mt++){
        float rs = rs_part[mt];
        rs += __shfl_xor(rs, 16);
        rs += __shfl_xor(rs, 32);
        rowsum[mt] = rs;           // full sum for q = mt*16 + (l&15), uniform across groups
    }
    const float gh = gate_h[h];
    float inv[2][4];
    #pragma unroll
    for (int mt=0;mt<2;mt++)
        #pragma unroll
        for (int r=0;r<4;r++)
            inv[mt][r] = gh / __shfl(rowsum[mt], (l>>4)*4 + r, 16);
    // epilogue: normalize, gate, write O[b][n][h*64+d]
    unsigned short* op = (unsigned short*)og + ((size_t)b*N_ + n0 + w*32)*C_ + h*64;
    #pragma unroll
    for (int mt=0;mt<2;mt++){
        #pragma unroll
        for (int r=0;r<4;r++){
            const int n = mt*16 + (l>>4)*4 + r;
            #pragma unroll
            for (int nt=0;nt<4;nt++)
                op[(size_t)n*C_ + nt*16 + (l&15)] = f2bf(o_acc[mt][nt][r]*inv[mt][r]);
        }
    }
}

// ---------------- launch ----------------
extern "C" void kernel_launch(void* const* d_in, const int* in_sizes, int n_in,
                              void* d_out, int out_size, void* d_ws, size_t ws_size,
                              hipStream_t stream)
{
    const float* x     = (const float*)d_in[0];
    const float* ln1g  = (const float*)d_in[1];
    const float* ln1b  = (const float*)d_in[2];
    const float* qkvw  = (const float*)d_in[3];
    const float* projw = (const float*)d_in[4];
    const float* projb = (const float*)d_in[5];
    const float* gateh = (const float*)d_in[6];
    const float* ln2g  = (const float*)d_in[7];
    const float* ln2b  = (const float*)d_in[8];
    const float* fc1w  = (const float*)d_in[9];
    const float* fc1b  = (const float*)d_in[10];
    const float* fc2w  = (const float*)d_in[11];
    const float* fc2b  = (const float*)d_in[12];
    const float* gatem = (const float*)d_in[13];
    float* out = (float*)d_out;

    char* ws = (char*)d_ws;
    __hip_bfloat16* h_buf = (__hip_bfloat16*)(ws + 0);          // 12.58MB  (h / h2)
    __hip_bfloat16* qkv   = (__hip_bfloat16*)(ws + 12582912);   // 37.75MB  (q,k,v^T)
    __hip_bfloat16* q_buf = qkv;
    __hip_bfloat16* k_buf = qkv + 6291456;
    __hip_bfloat16* vt_buf= qkv + 2*6291456;
    __hip_bfloat16* o_buf = (__hip_bfloat16*)(ws + 50331648);   // 12.58MB
    __hip_bfloat16* m_buf = (__hip_bfloat16*)(ws + 12582912);   // 50.33MB (reuses dead qkv+o)
    __hip_bfloat16* x1b   = (__hip_bfloat16*)(ws + 62914560);   // 12.58MB (bf16 residual)
    __hip_bfloat16* wqkv  = (__hip_bfloat16*)(ws + 88080384);
    __hip_bfloat16* wproj = (__hip_bfloat16*)(ws + 88965120);
    __hip_bfloat16* wfc1  = (__hip_bfloat16*)(ws + 89260032);
    __hip_bfloat16* wfc2  = (__hip_bfloat16*)(ws + 90439680);

    // LN1 + all weight converts, one launch (independent memory-bound tasks)
    ln1_cvt_kernel<<<5120, 256, 0, stream>>>(x, ln1g, ln1b, h_buf,
                                             qkvw, wqkv, 1152*384,
                                             projw, wproj, 384*384,
                                             fc1w, wfc1, 1536*384,
                                             fc2w, wfc2, 384*1536);

    // R9: per-op best-measured configs (QKV/proj: wres RT2; FC1: wres4 RT1; FC2: gemm_bt)
    gemm_wres<EPI_QKV,1152><<<1152, 256, 0, stream>>>(h_buf, wqkv, nullptr, nullptr, nullptr, qkv);
    attn_mfma<<<768, 256, 0, stream>>>(q_buf, k_buf, vt_buf, gateh, o_buf);
    gemm_wres<EPI_PROJ,384><<<384, 256, 0, stream>>>(o_buf, wproj, projb, x, nullptr, x1b);
    ln_kernel<__hip_bfloat16><<<4096, 256, 0, stream>>>(x1b, ln2g, ln2b, h_buf);
    gemm_wres4<EPI_FC1,1536><<<3072, 256, 0, stream>>>(h_buf, wfc1, fc1b, nullptr, gatem, m_buf);
    gemm_bt<EPI_FC2,64,128,3,1,256><<<768, 256, 0, stream>>>(m_buf, wfc2, R_, 384, 1536,
                                                             fc2b, nullptr, x1b, nullptr, out, nullptr);
}

// Round 11
// 169.345 us; speedup vs baseline: 1.1428x; 1.0259x over previous
//
#include <hip/hip_runtime.h>
#include <hip/hip_bf16.h>
#include <cstdint>
#include <cstddef>

#define B_   16
#define N_   1024
#define C_   384
#define H_   6
#define DFF_ 1536
#define R_   16384   // B_*N_

typedef __attribute__((ext_vector_type(8))) __bf16 bf16x8;
typedef __attribute__((ext_vector_type(4))) float  f32x4;
typedef __attribute__((ext_vector_type(8))) unsigned short u16x8;
typedef __attribute__((ext_vector_type(4))) unsigned short u16x4;

__device__ __forceinline__ float bf2f(unsigned short u){
    unsigned int x = ((unsigned int)u) << 16;
    return __builtin_bit_cast(float, x);
}
__device__ __forceinline__ unsigned short f2bf(float f){
    return __builtin_bit_cast(unsigned short, __float2bfloat16(f));
}
__device__ __forceinline__ unsigned int cvt_pk_bf16(float a, float b){
    unsigned int r;
    asm("v_cvt_pk_bf16_f32 %0, %1, %2" : "=v"(r) : "v"(a), "v"(b));
    return r;   // lo = bf16(a), hi = bf16(b)
}
// raw v_exp_f32 (2^x). Args provably in [-45,0] -> no OCML range/denorm fixup needed.
__device__ __forceinline__ float fast_exp2(float x){
    float r;
    asm("v_exp_f32 %0, %1" : "=v"(r) : "v"(x));
    return r;
}
__device__ __forceinline__ void gload16(const void* g, void* l){
    __builtin_amdgcn_global_load_lds(
        (const __attribute__((address_space(1))) unsigned int*)g,
        (__attribute__((address_space(3))) unsigned int*)l, 16, 0, 0);
}
// exact-GELU via Abramowitz-Stegun 7.1.25 erf approx (|err| <= 2.5e-5)
__device__ __forceinline__ float gelu_f(float u){
    float z  = fabsf(u) * 0.70710678118654752f;
    float t  = __builtin_amdgcn_rcpf(1.0f + 0.47047f*z);
    float e  = __expf(-z*z);
    float p  = t*(0.3480242f + t*(-0.0958798f + t*0.7478556f));
    float er = 1.0f - p*e;                       // erf(z), z>=0
    return 0.5f*u*(1.0f + copysignf(er, u));
}
__device__ __forceinline__ float ldv(const float* p, size_t i){ return p[i]; }
__device__ __forceinline__ float ldv(const __hip_bfloat16* p, size_t i){ return __bfloat162float(p[i]); }

// ---------------- LN1 + all-weight fp32->bf16 convert, one launch ----------------
__global__ __launch_bounds__(256) void ln1_cvt_kernel(
    const float* __restrict__ x, const float* __restrict__ g,
    const float* __restrict__ b, __hip_bfloat16* __restrict__ out,
    const float* __restrict__ i0, __hip_bfloat16* __restrict__ o0, int n0,
    const float* __restrict__ i1, __hip_bfloat16* __restrict__ o1, int n1,
    const float* __restrict__ i2, __hip_bfloat16* __restrict__ o2, int n2,
    const float* __restrict__ i3, __hip_bfloat16* __restrict__ o3, int n3)
{
    if (blockIdx.x < 4096){
        const int lane = threadIdx.x & 63;
        const int wave = threadIdx.x >> 6;
        const int row  = blockIdx.x*4 + wave;
        const float* xr = x + (size_t)row*C_;
        float v[6];
        float s = 0.f;
        #pragma unroll
        for (int i=0;i<6;i++){ v[i] = xr[lane + i*64]; s += v[i]; }
        #pragma unroll
        for (int m=1;m<64;m<<=1) s += __shfl_xor(s, m);
        const float mean = s * (1.0f/C_);
        float sq = 0.f;
        #pragma unroll
        for (int i=0;i<6;i++){ float d = v[i]-mean; sq += d*d; }
        #pragma unroll
        for (int m=1;m<64;m<<=1) sq += __shfl_xor(sq, m);
        const float rstd = rsqrtf(sq*(1.0f/C_) + 1e-5f);
        #pragma unroll
        for (int i=0;i<6;i++){
            int c = lane + i*64;
            out[(size_t)row*C_ + c] = __float2bfloat16((v[i]-mean)*rstd*g[c] + b[c]);
        }
    } else {
        const int total = n0+n1+n2+n3;
        for (int i = (blockIdx.x-4096)*blockDim.x + threadIdx.x; i < total; i += 1024*blockDim.x){
            int k = i;
            if (k < n0){ o0[k] = __float2bfloat16(i0[k]); continue; }
            k -= n0;
            if (k < n1){ o1[k] = __float2bfloat16(i1[k]); continue; }
            k -= n1;
            if (k < n2){ o2[k] = __float2bfloat16(i2[k]); continue; }
            k -= n2;
            o3[k] = __float2bfloat16(i3[k]);
        }
    }
}

// ---------------- LayerNorm: (fp32|bf16) in -> bf16 out ----------------
template<typename T>
__global__ __launch_bounds__(256) void ln_kernel(
    const T* __restrict__ x, const float* __restrict__ g,
    const float* __restrict__ b, __hip_bfloat16* __restrict__ out)
{
    const int lane = threadIdx.x & 63;
    const int wave = threadIdx.x >> 6;
    const int row  = blockIdx.x*4 + wave;
    const T* xr = x + (size_t)row*C_;
    float v[6];
    float s = 0.f;
    #pragma unroll
    for (int i=0;i<6;i++){ v[i] = ldv(xr, lane + i*64); s += v[i]; }
    #pragma unroll
    for (int m=1;m<64;m<<=1) s += __shfl_xor(s, m);
    const float mean = s * (1.0f/C_);
    float sq = 0.f;
    #pragma unroll
    for (int i=0;i<6;i++){ float d = v[i]-mean; sq += d*d; }
    #pragma unroll
    for (int m=1;m<64;m<<=1) sq += __shfl_xor(sq, m);
    const float rstd = rsqrtf(sq*(1.0f/C_) + 1e-5f);
    #pragma unroll
    for (int i=0;i<6;i++){
        int c = lane + i*64;
        out[(size_t)row*C_ + c] = __float2bfloat16((v[i]-mean)*rstd*g[c] + b[c]);
    }
}

enum { EPI_QKV=0, EPI_PROJ=1, EPI_FC2=3 };

// ---------------- per-op best-measured configs (R9 ledger) ----------------
// FC1: best = wres4 RT1 (~52us). QKV/proj: best = wres RT2 (R6/R9). FC2: R10's wres
// port RACED (self-paced wave overwrote shared B panel while others read it) ->
// R11 fix: barrier BEFORE STAGEB(q+1). Shared-mutable LDS needs read-side barrier
// even in the otherwise barrier-free structure; wave-private bands do not.

// gemm_wres: RT=2 -- B panel resident (stage-once, never overwritten), 4 A-bands
template<int EPI, int NCOLS>   // NCOLS: 1152 (QKV) / 384 (proj)
__global__ __launch_bounds__(256, 2) void gemm_wres(
    const __hip_bfloat16* __restrict__ A,    // [16384, 384]
    const __hip_bfloat16* __restrict__ Wt,   // [NCOLS, 384]
    const float* __restrict__ bias,
    const float* __restrict__ resid,
    const float* __restrict__ gate,
    __hip_bfloat16* __restrict__ outb)
{
    constexpr int NB = NCOLS/64;             // col-blocks
    constexpr int G  = 24;                   // RT=2 tiles x 12 K-steps
    __shared__ __align__(16) unsigned short As[4][128*32];   // 32KB: 4 bands, wave-private 32rx32k
    __shared__ __align__(16) unsigned short Bs[64*384];      // 48KB: whole-K weight panel
    const int t = threadIdx.x;
    const int l = t & 63;
    const int w = t >> 6;
    const int X  = blockIdx.x & 7;
    const int j8 = blockIdx.x >> 3;
    const int rb = X*8 + j8 / NB;            // row-group 0..63 (256 rows each)
    const int cb = j8 % NB;

    // ---- B panel: whole K staged once, 12 gload16/thread, pre-swizzled source ----
    #pragma unroll
    for (int j=0;j<12;j++){
        const int L     = (w*12 + j)*1024 + l*16;       // linear LDS byte (gload_lds HW rule)
        const int row   = L / 768;                      // B row 0..63
        const int cbyte = L - row*768;
        const int scol  = (cbyte ^ ((row&7)<<4)) >> 1;  // inverse-swizzled source col (elems)
        gload16(Wt + (size_t)(cb*64 + row)*384 + scol, (char*)&Bs[0] + L);
    }
    // ---- A bands: wave-private, 2 gload16 per band (32 rows x 32 K) ----
    const int sgcol = (((l&3) - ((l>>3)&3)) & 3) * 8;
    const size_t arow0 = (size_t)rb*256 + w*32 + (l>>2);
    auto STAGEA = [&](int g){
        const int rt = g/12, s = g - rt*12;
        #pragma unroll
        for (int c=0;c<2;c++)
            gload16(A + (arow0 + rt*128 + c*16)*384 + s*32 + sgcol,
                    (char*)&As[g&3][0] + w*2048 + c*1024 + l*16);
    };
    STAGEA(0); STAGEA(1); STAGEA(2);
    asm volatile("s_waitcnt vmcnt(6)" ::: "memory");    // 12 B loads drained; 3 bands in flight
    __builtin_amdgcn_s_barrier();                        // the ONLY barrier

    #pragma unroll
    for (int rt=0; rt<2; ++rt){
        f32x4 acc[2][4];
        #pragma unroll
        for (int i=0;i<2;i++)
            #pragma unroll
            for (int jj=0;jj<4;jj++) acc[i][jj] = (f32x4){0.f,0.f,0.f,0.f};

        #pragma unroll
        for (int s=0; s<12; ++s){
            const int g = rt*12 + s;
            if (g <= G-3)      asm volatile("s_waitcnt vmcnt(4)" ::: "memory");  // band g ready; 2 newer in flight
            else if (g == G-2) asm volatile("s_waitcnt vmcnt(2)" ::: "memory");
            else               asm volatile("s_waitcnt vmcnt(0)" ::: "memory");
            const char* as = (const char*)&As[g&3][0] + w*2048;
            bf16x8 af[2], bw[4];
            #pragma unroll
            for (int i=0;i<2;i++){
                const int r  = i*16 + (l&15);
                const int sl = ((l>>4) + ((r>>1)&3)) & 3;
                af[i] = *(const bf16x8*)(as + r*64 + sl*16);
            }
            #pragma unroll
            for (int i=0;i<4;i++){
                const int r = i*16 + (l&15);                  // B row (output col) 0..63
                bw[i] = *(const bf16x8*)((const char*)&Bs[0] + r*768
                             + ((s*64 + (l>>4)*16) ^ ((r&7)<<4)));
            }
            #pragma unroll
            for (int mi=0;mi<2;mi++)
                #pragma unroll
                for (int ni=0;ni<4;ni++)
                    acc[mi][ni] = __builtin_amdgcn_mfma_f32_16x16x32_bf16(af[mi], bw[ni], acc[mi][ni], 0,0,0);
            asm volatile("s_waitcnt lgkmcnt(0)" ::: "memory");  // own ds_reads retired before band overwrite
            if (g+3 < G) STAGEA(g+3);
        }
        // ---- per-tile epilogue ----
        const int rowBase = rb*256 + rt*128 + w*32;
        if constexpr (EPI==EPI_QKV){
            // scatter: Q,K -> [p][B][H][N][64]; V (p==2) -> [B][H][64][N] (transposed)
            unsigned short* ob = (unsigned short*)outb;
            #pragma unroll
            for (int ni=0; ni<4; ni++){
                const int col = cb*64 + ni*16 + (l&15);
                const int p = col/384, rem = col - p*384;
                const int hh = rem>>6, d = rem&63;
                #pragma unroll
                for (int mi=0; mi<2; mi++){
                    const int row0 = rowBase + mi*16 + (l>>4)*4;
                    const int bb = row0>>10, n = row0&1023;
                    if (p==2){
                        u16x4 pk;
                        #pragma unroll
                        for (int jj=0;jj<4;jj++) pk[jj] = f2bf(acc[mi][ni][jj]);
                        *(u16x4*)(ob + (size_t)2*6291456 + ((size_t)(bb*H_+hh)*64 + d)*1024 + n) = pk;
                    } else {
                        #pragma unroll
                        for (int jj=0;jj<4;jj++)
                            ob[(((size_t)((p*16+bb)*6+hh))<<16) + ((size_t)(n+jj)<<6) + d] = f2bf(acc[mi][ni][jj]);
                    }
                }
            }
        } else {
            #pragma unroll
            for (int ni=0; ni<4; ni++){
                const int col = cb*64 + ni*16 + (l&15);
                #pragma unroll
                for (int mi=0; mi<2; mi++){
                    #pragma unroll
                    for (int jj=0;jj<4;jj++){
                        const int row = rowBase + mi*16 + (l>>4)*4 + jj;
                        const size_t idx = (size_t)row*NCOLS + col;
                        outb[idx] = __float2bfloat16(resid[idx] + acc[mi][ni][jj] + bias[col]); // EPI_PROJ
                    }
                }
            }
        }
    }
}

// gemm_wres4: RT=1 -- B panel resident, 4 A-bands deep lead, epilogue after loop (FC1)
template<int NCOLS>   // 1536 (FC1)
__global__ __launch_bounds__(256, 2) void gemm_wres4(
    const __hip_bfloat16* __restrict__ A,    // [16384, 384]
    const __hip_bfloat16* __restrict__ Wt,   // [NCOLS, 384]
    const float* __restrict__ bias,
    const float* __restrict__ gate,
    __hip_bfloat16* __restrict__ outb)
{
    constexpr int NB = NCOLS/64;             // col-blocks
    __shared__ __align__(16) unsigned short As[4][128*32];   // 32KB: 4 bands, wave-private 32rx32k
    __shared__ __align__(16) unsigned short Bs[64*384];      // 48KB: whole-K weight panel
    const int t = threadIdx.x;
    const int l = t & 63;
    const int w = t >> 6;
    const int X  = blockIdx.x & 7;
    const int j8 = blockIdx.x >> 3;
    const int rb = X*16 + j8 / NB;           // row-block 0..127 (128 rows each)
    const int cb = j8 % NB;

    // ---- B panel: whole K staged once, 12 gload16/thread, pre-swizzled source ----
    #pragma unroll
    for (int j=0;j<12;j++){
        const int L     = (w*12 + j)*1024 + l*16;       // linear LDS byte (gload_lds HW rule)
        const int row   = L / 768;                      // B row 0..63
        const int cbyte = L - row*768;
        const int scol  = (cbyte ^ ((row&7)<<4)) >> 1;  // inverse-swizzled source col (elems)
        gload16(Wt + (size_t)(cb*64 + row)*384 + scol, (char*)&Bs[0] + L);
    }
    // ---- A bands: wave-private, 2 gload16 per band (32 rows x 32 K) ----
    const int sgcol = (((l&3) - ((l>>3)&3)) & 3) * 8;
    const size_t arow0 = (size_t)rb*128 + w*32 + (l>>2);
    auto STAGEA = [&](int g){
        #pragma unroll
        for (int c=0;c<2;c++)
            gload16(A + (arow0 + c*16)*384 + g*32 + sgcol,
                    (char*)&As[g&3][0] + w*2048 + c*1024 + l*16);
    };
    STAGEA(0); STAGEA(1); STAGEA(2);
    asm volatile("s_waitcnt vmcnt(6)" ::: "memory");    // 12 B loads drained; 3 bands in flight
    __builtin_amdgcn_s_barrier();                        // the ONLY barrier

    f32x4 acc[2][4];
    #pragma unroll
    for (int i=0;i<2;i++)
        #pragma unroll
        for (int jj=0;jj<4;jj++) acc[i][jj] = (f32x4){0.f,0.f,0.f,0.f};

    #pragma unroll
    for (int s=0; s<12; ++s){
        if (s < 10)      asm volatile("s_waitcnt vmcnt(4)" ::: "memory");  // band s ready; 2 newer in flight
        else if (s == 10) asm volatile("s_waitcnt vmcnt(2)" ::: "memory");
        else              asm volatile("s_waitcnt vmcnt(0)" ::: "memory");
        const char* as = (const char*)&As[s&3][0] + w*2048;
        bf16x8 af[2], bw[4];
        #pragma unroll
        for (int i=0;i<2;i++){
            const int r  = i*16 + (l&15);                 // local band row 0..31
            const int sl = ((l>>4) + ((r>>1)&3)) & 3;
            af[i] = *(const bf16x8*)(as + r*64 + sl*16);
        }
        #pragma unroll
        for (int i=0;i<4;i++){
            const int r = i*16 + (l&15);                  // B row (output col) 0..63
            bw[i] = *(const bf16x8*)((const char*)&Bs[0] + r*768
                         + ((s*64 + (l>>4)*16) ^ ((r&7)<<4)));
        }
        #pragma unroll
        for (int mi=0;mi<2;mi++)
            #pragma unroll
            for (int ni=0;ni<4;ni++)
                acc[mi][ni] = __builtin_amdgcn_mfma_f32_16x16x32_bf16(af[mi], bw[ni], acc[mi][ni], 0,0,0);
        asm volatile("s_waitcnt lgkmcnt(0)" ::: "memory");  // own ds_reads retired before band overwrite
        if (s+3 < 12) STAGEA(s+3);                          // writes band (s-1)&3, reads retired at s-1
    }

    // ---- epilogue (after loop: stores cannot poison counted waits) ----
    const int rowBase = rb*128 + w*32;
    #pragma unroll
    for (int ni=0; ni<4; ni++){
        const int col = cb*64 + ni*16 + (l&15);
        #pragma unroll
        for (int mi=0; mi<2; mi++){
            #pragma unroll
            for (int jj=0;jj<4;jj++){
                const int row = rowBase + mi*16 + (l>>4)*4 + jj;
                const size_t idx = (size_t)row*NCOLS + col;
                outb[idx] = __float2bfloat16(gelu_f(acc[mi][ni][jj] + bias[col]) * gate[col]); // FC1
            }
        }
    }
}

// ---------------- R11: FC2 wres, 4 K-chunked B panels -- RACE-FIXED ----------------
// R10 race: STAGEB(q+1) was issued per-wave right after ITS s-loop -> fast wave
// overwrote shared Bs while slow waves still read chunk q (absmax 0.289, nondet).
// Fix: barrier BEFORE STAGEB(q+1). Per boundary: [s=11 lgkmcnt(0) retires own
// ds_reads] -> s_barrier (all waves' reads done) -> STAGEB(q+1) -> vmcnt(0) ->
// s_barrier (panel ready). 8 barriers/block total vs gemm_bt's 96. A-band pipeline
// (wave-private) still crosses boundaries uninterrupted; pre-issued bands for the
// next chunk's s=0..2 simply land during the boundary vmcnt(0) -> those steps skip waits.
__global__ __launch_bounds__(256, 2) void gemm_wres_fc2(
    const __hip_bfloat16* __restrict__ A,      // m_buf [16384, 1536]
    const __hip_bfloat16* __restrict__ Wt,     // fc2w  [384, 1536]
    const float* __restrict__ bias,            // [384]
    const __hip_bfloat16* __restrict__ residb, // x1b [16384, 384]
    float* __restrict__ outf)                  // out [16384, 384] fp32
{
    constexpr int NB = 6;                    // 384/64 col-blocks
    __shared__ __align__(16) unsigned short As[4][128*32];   // 32KB: 4 bands
    __shared__ __align__(16) unsigned short Bs[64*384];      // 48KB: one K-chunk of B
    const int t = threadIdx.x;
    const int l = t & 63;
    const int w = t >> 6;
    const int X  = blockIdx.x & 7;
    const int j8 = blockIdx.x >> 3;          // 0..95
    const int rb = X*16 + j8 / NB;           // row-block 0..127
    const int cb = j8 % NB;

    auto STAGEB = [&](int q){                // chunk q: cols q*384..q*384+383 of each B row
        #pragma unroll
        for (int j=0;j<12;j++){
            const int L     = (w*12 + j)*1024 + l*16;
            const int row   = L / 768;
            const int cbyte = L - row*768;
            const int scol  = (cbyte ^ ((row&7)<<4)) >> 1;
            gload16(Wt + (size_t)(cb*64 + row)*1536 + q*384 + scol, (char*)&Bs[0] + L);
        }
    };
    const int sgcol = (((l&3) - ((l>>3)&3)) & 3) * 8;
    const size_t arow0 = (size_t)rb*128 + w*32 + (l>>2);
    auto STAGEA = [&](int g){                // global K-step g in [0,48)
        #pragma unroll
        for (int c=0;c<2;c++)
            gload16(A + (arow0 + c*16)*1536 + g*32 + sgcol,
                    (char*)&As[g&3][0] + w*2048 + c*1024 + l*16);
    };

    STAGEB(0);
    STAGEA(0); STAGEA(1); STAGEA(2);
    asm volatile("s_waitcnt vmcnt(0)" ::: "memory");
    __builtin_amdgcn_s_barrier();
    asm volatile("" ::: "memory");

    f32x4 acc[2][4];
    #pragma unroll
    for (int i=0;i<2;i++)
        #pragma unroll
        for (int jj=0;jj<4;jj++) acc[i][jj] = (f32x4){0.f,0.f,0.f,0.f};

    for (int q=0; q<4; ++q){
        if (q > 0){
            asm volatile("s_waitcnt vmcnt(0)" ::: "memory");   // B(q) + pre-issued bands landed
            __builtin_amdgcn_s_barrier();                       // panel ready for all waves
            asm volatile("" ::: "memory");
        }
        #pragma unroll
        for (int s=0; s<12; ++s){
            const int g = q*12 + s;
            if (s >= 3){                       // s<3: band pre-staged and drained at boundary
                if (g < 46)      asm volatile("s_waitcnt vmcnt(4)" ::: "memory");
                else if (g == 46) asm volatile("s_waitcnt vmcnt(2)" ::: "memory");
                else              asm volatile("s_waitcnt vmcnt(0)" ::: "memory");
            }
            const char* as = (const char*)&As[g&3][0] + w*2048;
            bf16x8 af[2], bw[4];
            #pragma unroll
            for (int i=0;i<2;i++){
                const int r  = i*16 + (l&15);
                const int sl = ((l>>4) + ((r>>1)&3)) & 3;
                af[i] = *(const bf16x8*)(as + r*64 + sl*16);
            }
            #pragma unroll
            for (int i=0;i<4;i++){
                const int r = i*16 + (l&15);
                bw[i] = *(const bf16x8*)((const char*)&Bs[0] + r*768
                             + ((s*64 + (l>>4)*16) ^ ((r&7)<<4)));
            }
            #pragma unroll
            for (int mi=0;mi<2;mi++)
                #pragma unroll
                for (int ni=0;ni<4;ni++)
                    acc[mi][ni] = __builtin_amdgcn_mfma_f32_16x16x32_bf16(af[mi], bw[ni], acc[mi][ni], 0,0,0);
            asm volatile("s_waitcnt lgkmcnt(0)" ::: "memory");  // own ds_reads retired before overwrites
            if (g+3 < 48) STAGEA(g+3);
        }
        if (q < 3){
            __builtin_amdgcn_s_barrier();      // RACE FIX: ALL waves done reading Bs chunk q
            asm volatile("" ::: "memory");
            STAGEB(q+1);                       // now safe to overwrite shared panel
        }
    }

    // ---- epilogue: residual (bf16) + bias -> fp32 out ----
    const int rowBase = rb*128 + w*32;
    const unsigned short* xb = (const unsigned short*)residb;
    #pragma unroll
    for (int ni=0; ni<4; ni++){
        const int col = cb*64 + ni*16 + (l&15);
        #pragma unroll
        for (int mi=0; mi<2; mi++){
            #pragma unroll
            for (int jj=0;jj<4;jj++){
                const int row = rowBase + mi*16 + (l>>4)*4 + jj;
                const size_t idx = (size_t)row*384 + col;
                outf[idx] = bf2f(xb[idx]) + acc[mi][ni][jj] + bias[col];
            }
        }
    }
}

// ---------------- MFMA flash attention, 3-buffer single-barrier pipeline (R12-best) ----------------
// QBLK=128 (grid 768): 4 waves, wave w owns 32 q-rows. In-register P via swapped QK^T
// + phys_k permutation (lane-local k-ownership -> P packed via v_cvt_pk_bf16_f32).
// Per-lane rs_part denominators, reduced once after the loop. VGPR 72 -> 3 blocks/CU
// (register cliff: do NOT add live state). exp via raw v_exp_f32 (R12 win).
__global__ __launch_bounds__(256) void attn_mfma(
    const __hip_bfloat16* __restrict__ qg,   // [B,H,N,64]
    const __hip_bfloat16* __restrict__ kg,   // [B,H,N,64]
    const __hip_bfloat16* __restrict__ vtg,  // [B,H,64,N]
    const float* __restrict__ gate_h,
    __hip_bfloat16* __restrict__ og)         // [B,N,C]
{
    __shared__ __align__(16) unsigned short Ks [3][64*64];
    __shared__ __align__(16) unsigned short Vts[3][64*64];
    const int t = threadIdx.x;
    const int l = t & 63;
    const int w = t >> 6;
    // XCD swizzle: 96 bh over 8 XCDs = 12 bh/XCD, 8 q-tiles each contiguous
    const int X  = blockIdx.x & 7;
    const int j8 = blockIdx.x >> 3;          // 0..95
    const int bh = X*12 + (j8 >> 3);
    const int n0 = (j8 & 7) * 128;
    const int h  = bh % H_;
    const int b  = bh / H_;
    const unsigned short* qp  = (const unsigned short*)qg  + ((size_t)bh*N_ + n0 + w*32)*64;
    const unsigned short* kp  = (const unsigned short*)kg  + (size_t)bh*N_*64;
    const unsigned short* vtp = (const unsigned short*)vtg + (size_t)bh*64*N_;

    // Q fragments (B-operand layout), scale*log2e folded in
    bf16x8 qf[2][2];
    #pragma unroll
    for (int mt=0;mt<2;mt++)
        #pragma unroll
        for (int dc=0;dc<2;dc++){
            u16x8 raw = *(const u16x8*)(qp + ((size_t)(mt*16 + (l&15)))*64 + dc*32 + (l>>4)*8);
            u16x8 sc;
            #pragma unroll
            for (int j=0;j<8;j++) sc[j] = f2bf(bf2f(raw[j]) * 0.1803368801111244f);
            qf[mt][dc] = __builtin_bit_cast(bf16x8, sc);
        }

    // pre-hoisted ds_read byte offsets (lane-dependent, kt-invariant)
    int qk_off[4][2], pv_off[2][4];
    #pragma unroll
    for (int t4=0;t4<4;t4++){
        const int i    = l & 15;
        const int row  = 8*(i>>2) + (i&3) + 4*(t4&1) + 32*(t4>>1);   // phys_k(t4, i)
        const int swzr = (row&3) | (((row>>3)&1)<<2);
        #pragma unroll
        for (int dc=0;dc<2;dc++)
            qk_off[t4][dc] = row*128 + ((dc*64 + (l>>4)*16) ^ (swzr<<4));
    }
    #pragma unroll
    for (int nt=0;nt<4;nt++){
        const int row  = nt*16 + (l&15);
        const int swzr = (row&3) | (((row>>3)&1)<<2);
        #pragma unroll
        for (int kc=0;kc<2;kc++)
            pv_off[kc][nt] = row*128 + ((kc*64 + (l>>4)*16) ^ (swzr<<4));
    }

    const int sr  = t >> 3;        // staging row 0..31 (and +32)
    const int sce = (t & 7) * 8;   // staging col (elements) before swizzle

    auto STAGE = [&](int buf, int kt){
        #pragma unroll
        for (int c=0;c<2;c++){
            const int r    = sr + c*32;
            const int swzr = (r&3) | (((r>>3)&1)<<2);
            const int col  = sce ^ (swzr<<3);           // inverse-swizzled global col
            gload16(kp  + ((size_t)(kt*64 + r))*64 + col, (char*)&Ks [buf][0] + (c*256 + t)*16);
            gload16(vtp + (size_t)r*N_ + kt*64 + col,     (char*)&Vts[buf][0] + (c*256 + t)*16);
        }
    };

    f32x4 o_acc[2][4];
    #pragma unroll
    for (int i=0;i<2;i++)
        #pragma unroll
        for (int jj=0;jj<4;jj++) o_acc[i][jj] = (f32x4){0.f,0.f,0.f,0.f};
    float rs_part[2] = {0.f, 0.f};   // per-lane partial denominators (k is lane-local)

    STAGE(0, 0);
    STAGE(1, 1);
    int cur = 0, stb = 2;
    for (int kt=0; kt<16; kt++){
        if (kt < 15) asm volatile("s_waitcnt vmcnt(4)" ::: "memory");  // own tile done; next in flight
        else         asm volatile("s_waitcnt vmcnt(0)" ::: "memory");
        __builtin_amdgcn_s_barrier();
        asm volatile("" ::: "memory");
        if (kt < 14){
            STAGE(stb, kt+2);
            stb = (stb+1==3) ? 0 : stb+1;
        }
        const char* ks = (const char*)&Ks[cur][0];
        const char* vs = (const char*)&Vts[cur][0];

        // QK^T (swapped): A=K (permuted rows), B=Q
        f32x4 s_acc[4][2];
        #pragma unroll
        for (int i=0;i<4;i++)
            #pragma unroll
            for (int jj=0;jj<2;jj++) s_acc[i][jj] = (f32x4){0.f,0.f,0.f,0.f};
        #pragma unroll
        for (int t4=0;t4<4;t4++)
            #pragma unroll
            for (int dc=0;dc<2;dc++){
                bf16x8 kf = *(const bf16x8*)(ks + qk_off[t4][dc]);
                #pragma unroll
                for (int mt=0;mt<2;mt++)
                    s_acc[t4][mt] = __builtin_amdgcn_mfma_f32_16x16x32_bf16(kf, qf[mt][dc], s_acc[t4][mt], 0,0,0);
            }
        // exp via raw v_exp_f32 (scale pre-folded; scores bounded) + per-lane partials
        #pragma unroll
        for (int mt=0;mt<2;mt++){
            float acc_s = 0.f;
            #pragma unroll
            for (int t4=0;t4<4;t4++){
                #pragma unroll
                for (int jj=0;jj<4;jj++){
                    float e = fast_exp2(s_acc[t4][mt][jj]);
                    s_acc[t4][mt][jj] = e;
                    acc_s += e;
                }
            }
            rs_part[mt] += acc_s;
        }
        // PV: P-fragments packed in-register (lane-local k-ownership)
        #pragma unroll
        for (int kc=0;kc<2;kc++){
            union { unsigned int u[4]; bf16x8 v; } pu[2];
            #pragma unroll
            for (int mt=0;mt<2;mt++){
                pu[mt].u[0] = cvt_pk_bf16(s_acc[2*kc  ][mt][0], s_acc[2*kc  ][mt][1]);
                pu[mt].u[1] = cvt_pk_bf16(s_acc[2*kc  ][mt][2], s_acc[2*kc  ][mt][3]);
                pu[mt].u[2] = cvt_pk_bf16(s_acc[2*kc+1][mt][0], s_acc[2*kc+1][mt][1]);
                pu[mt].u[3] = cvt_pk_bf16(s_acc[2*kc+1][mt][2], s_acc[2*kc+1][mt][3]);
            }
            #pragma unroll
            for (int nt=0;nt<4;nt++){
                bf16x8 vf = *(const bf16x8*)(vs + pv_off[kc][nt]);
                #pragma unroll
                for (int mt=0;mt<2;mt++)
                    o_acc[mt][nt] = __builtin_amdgcn_mfma_f32_16x16x32_bf16(pu[mt].v, vf, o_acc[mt][nt], 0,0,0);
            }
        }
        cur = (cur+1==3) ? 0 : cur+1;
    }
    // final denominator: reduce across the 4 lane-groups, then broadcast to output layout
    float rowsum[2];
    #pragma unroll
    for (int mt=0;mt<2;mt++){
        float rs = rs_part[mt];
        rs += __shfl_xor(rs, 16);
        rs += __shfl_xor(rs, 32);
        rowsum[mt] = rs;           // full sum for q = mt*16 + (l&15), uniform across groups
    }
    const float gh = gate_h[h];
    float inv[2][4];
    #pragma unroll
    for (int mt=0;mt<2;mt++)
        #pragma unroll
        for (int r=0;r<4;r++)
            inv[mt][r] = gh / __shfl(rowsum[mt], (l>>4)*4 + r, 16);
    // epilogue: normalize, gate, write O[b][n][h*64+d]
    unsigned short* op = (unsigned short*)og + ((size_t)b*N_ + n0 + w*32)*C_ + h*64;
    #pragma unroll
    for (int mt=0;mt<2;mt++){
        #pragma unroll
        for (int r=0;r<4;r++){
            const int n = mt*16 + (l>>4)*4 + r;
            #pragma unroll
            for (int nt=0;nt<4;nt++)
                op[(size_t)n*C_ + nt*16 + (l&15)] = f2bf(o_acc[mt][nt][r]*inv[mt][r]);
        }
    }
}

// ---------------- launch ----------------
extern "C" void kernel_launch(void* const* d_in, const int* in_sizes, int n_in,
                              void* d_out, int out_size, void* d_ws, size_t ws_size,
                              hipStream_t stream)
{
    const float* x     = (const float*)d_in[0];
    const float* ln1g  = (const float*)d_in[1];
    const float* ln1b  = (const float*)d_in[2];
    const float* qkvw  = (const float*)d_in[3];
    const float* projw = (const float*)d_in[4];
    const float* projb = (const float*)d_in[5];
    const float* gateh = (const float*)d_in[6];
    const float* ln2g  = (const float*)d_in[7];
    const float* ln2b  = (const float*)d_in[8];
    const float* fc1w  = (const float*)d_in[9];
    const float* fc1b  = (const float*)d_in[10];
    const float* fc2w  = (const float*)d_in[11];
    const float* fc2b  = (const float*)d_in[12];
    const float* gatem = (const float*)d_in[13];
    float* out = (float*)d_out;

    char* ws = (char*)d_ws;
    __hip_bfloat16* h_buf = (__hip_bfloat16*)(ws + 0);          // 12.58MB  (h / h2)
    __hip_bfloat16* qkv   = (__hip_bfloat16*)(ws + 12582912);   // 37.75MB  (q,k,v^T)
    __hip_bfloat16* q_buf = qkv;
    __hip_bfloat16* k_buf = qkv + 6291456;
    __hip_bfloat16* vt_buf= qkv + 2*6291456;
    __hip_bfloat16* o_buf = (__hip_bfloat16*)(ws + 50331648);   // 12.58MB
    __hip_bfloat16* m_buf = (__hip_bfloat16*)(ws + 12582912);   // 50.33MB (reuses dead qkv+o)
    __hip_bfloat16* x1b   = (__hip_bfloat16*)(ws + 62914560);   // 12.58MB (bf16 residual)
    __hip_bfloat16* wqkv  = (__hip_bfloat16*)(ws + 88080384);
    __hip_bfloat16* wproj = (__hip_bfloat16*)(ws + 88965120);
    __hip_bfloat16* wfc1  = (__hip_bfloat16*)(ws + 89260032);
    __hip_bfloat16* wfc2  = (__hip_bfloat16*)(ws + 90439680);

    // LN1 + all weight converts, one launch (independent memory-bound tasks)
    ln1_cvt_kernel<<<5120, 256, 0, stream>>>(x, ln1g, ln1b, h_buf,
                                             qkvw, wqkv, 1152*384,
                                             projw, wproj, 384*384,
                                             fc1w, wfc1, 1536*384,
                                             fc2w, wfc2, 384*1536);

    // R11: FC2 wres with race fix (barrier before B-panel overwrite); rest = R9
    gemm_wres<EPI_QKV,1152><<<1152, 256, 0, stream>>>(h_buf, wqkv, nullptr, nullptr, nullptr, qkv);
    attn_mfma<<<768, 256, 0, stream>>>(q_buf, k_buf, vt_buf, gateh, o_buf);
    gemm_wres<EPI_PROJ,384><<<384, 256, 0, stream>>>(o_buf, wproj, projb, x, nullptr, x1b);
    ln_kernel<__hip_bfloat16><<<4096, 256, 0, stream>>>(x1b, ln2g, ln2b, h_buf);
    gemm_wres4<1536><<<3072, 256, 0, stream>>>(h_buf, wfc1, fc1b, gatem, m_buf);
    gemm_wres_fc2<<<768, 256, 0, stream>>>(m_buf, wfc2, fc2b, x1b, out);
}